// Round 1
// baseline (2604.634 us; speedup 1.0000x reference)
//
#include <hip/hip_runtime.h>

#define KK 1023
#define LL 8184
#define LO 7162
#define EPSF 1.1920928955078125e-07f
#define NEG_INF (-3.4028234663852886e+38f)

__device__ __constant__ int c_pos[16] = {0,409,818,1227,1636,2045,2454,2863,
                                         3273,3682,4091,4500,4909,5318,5727,6137};

// ---------------- K0: zero the code histogram ----------------
__global__ void k_init(int* __restrict__ hist) {
    hist[threadIdx.x] = 0;
}

// ---------------- K1: frames -> windowed/normalized -> circular autocorr -> Z
// 2 blocks per frame (each block does 512 of the 1023 lags). Direct O(n^2)
// replaces rfft->|F|^2->irfft->ifftshift exactly (Wiener-Khinchin).
__global__ __launch_bounds__(256) void k_autocov(const float* __restrict__ X,
                                                 float* __restrict__ Z) {
    __shared__ float xw[2046];
    __shared__ float red[256];
    const int fi   = blockIdx.x >> 1;
    const int half = blockIdx.x & 1;
    const int b = fi >> 4, h = fi & 15;
    const int tid = threadIdx.x;
    const float* xp = X + b * LL + c_pos[h];

    float lmax = 0.f;
    for (int j = tid; j < KK; j += 256) {
        float v = xp[j];
        xw[j] = v;
        lmax = fmaxf(lmax, fabsf(v));
    }
    red[tid] = lmax;
    __syncthreads();
    for (int off = 128; off; off >>= 1) {
        if (tid < off) red[tid] = fmaxf(red[tid], red[tid + off]);
        __syncthreads();
    }
    float fmax = red[0];
    if (fmax == 0.f) fmax = EPSF;
    __syncthreads();
    for (int j = tid; j < KK; j += 256) {
        float v = xw[j];
        float win = 0.5f * (1.0f - cosf(6.28318530717958647692f * (float)j / 1023.0f));
        float w = v * win / fmax;
        xw[j] = w;
        xw[j + KK] = w;   // duplicate so c[m] = sum_j xw[j]*xw[j+m], no modulo
    }
    __syncthreads();

    const int m1 = half * 512 + tid;
    const int m2 = m1 + 256;
    float a0 = 0.f, a1 = 0.f;
#pragma unroll 8
    for (int j = 0; j < KK; ++j) {
        float xj = xw[j];
        a0 = fmaf(xj, xw[j + m1], a0);
        a1 = fmaf(xj, xw[j + m2], a1);
    }
    float* zrow = Z + fi * KK;
    int i1 = m1 + 512; if (i1 >= KK) i1 -= KK;   // Z[i] = c[(i+511)%1023]
    zrow[i1] = a0;
    if (m2 < KK) {
        int i2 = m2 + 512; if (i2 >= KK) i2 -= KK;
        zrow[i2] = a1;
    }
}

// ---------------- K2: VQ argmin + vq-loss partial + histogram ----------------
__global__ __launch_bounds__(256) void k_vq(const float* __restrict__ Z,
                                            const float* __restrict__ emb,
                                            int* __restrict__ codes,
                                            int* __restrict__ hist,
                                            float* __restrict__ vq_part) {
    __shared__ float zl[KK];
    __shared__ float rv[256];
    __shared__ int   ri[256];
    const int fi = blockIdx.x, tid = threadIdx.x;
    const float* zrow = Z + fi * KK;
    for (int t = tid; t < KK; t += 256) zl[t] = zrow[t];
    __syncthreads();

    // d'_e = ||e||^2 - 2 z.e (same argmin as full distance)
    const float* er = emb + tid * KK;
    float d = 0.f;
#pragma unroll 4
    for (int t = 0; t < KK; ++t) {
        float e = er[t];
        d = fmaf(e, e - 2.f * zl[t], d);
    }
    rv[tid] = d; ri[tid] = tid;
    __syncthreads();
    for (int off = 128; off; off >>= 1) {
        if (tid < off) {
            float v2 = rv[tid + off]; int i2 = ri[tid + off];
            if (v2 < rv[tid] || (v2 == rv[tid] && i2 < ri[tid])) { rv[tid] = v2; ri[tid] = i2; }
        }
        __syncthreads();
    }
    const int code = ri[0];
    if (tid == 0) { codes[fi] = code; atomicAdd(&hist[code], 1); }

    const float* qr = emb + code * KK;
    float s = 0.f;
    for (int t = tid; t < KK; t += 256) { float dd = qr[t] - zl[t]; s += dd * dd; }
    __syncthreads();
    rv[tid] = s;
    __syncthreads();
    for (int off = 128; off; off >>= 1) {
        if (tid < off) rv[tid] += rv[tid + off];
        __syncthreads();
    }
    if (tid == 0) vq_part[fi] = rv[0];
}

// ---------------- K3: big SAME conv (filters = quant rows) fused with recon partial
// grid = 8 n * 128 f * 4 ltiles; 256 thr; 8 outputs/thread.
__global__ __launch_bounds__(256) void k_conv_recon(const float* __restrict__ X,
                                                    const float* __restrict__ emb,
                                                    const int* __restrict__ codes,
                                                    float* __restrict__ recon_part) {
    __shared__ float xl[3072];
    __shared__ float ql[1024];
    __shared__ float red[256];
    const int bi = blockIdx.x;
    const int n    = bi >> 9;
    const int f    = (bi >> 2) & 127;
    const int tile = bi & 3;
    const int tid  = threadIdx.x;
    const int tbase = tile * 2048;
    const int gs = tbase - 511;                 // SAME pad 511
    const float* xrow = X + n * LL;
    for (int k = tid; k < 3072; k += 256) {
        int g = gs + k;
        xl[k] = (g >= 0 && g < LL) ? xrow[g] : 0.f;
    }
    const int code = codes[f];
    const float* qr = emb + code * KK;
    for (int t = tid; t < KK; t += 256) ql[t] = qr[t];
    __syncthreads();

    float acc[8] = {0,0,0,0,0,0,0,0};
    const int mo = tid * 8;
    int t = 0;
    for (; t + 8 <= KK; t += 8) {
#pragma unroll
        for (int tt = 0; tt < 8; ++tt) {
            float qv = ql[t + tt];
#pragma unroll
            for (int i = 0; i < 8; ++i) acc[i] = fmaf(xl[mo + t + tt + i], qv, acc[i]);
        }
    }
    for (; t < KK; ++t) {
        float qv = ql[t];
#pragma unroll
        for (int i = 0; i < 8; ++i) acc[i] = fmaf(xl[mo + t + i], qv, acc[i]);
    }
    float s = 0.f;
#pragma unroll
    for (int i = 0; i < 8; ++i) {
        int l = tbase + mo + i;
        if (l < LL) {
            float d = acc[i] - xl[mo + i + 511];   // X[n,l]
            s += d * d;
        }
    }
    red[tid] = s;
    __syncthreads();
    for (int off = 128; off; off >>= 1) {
        if (tid < off) red[tid] += red[tid + off];
        __syncthreads();
    }
    if (tid == 0) recon_part[bi] = red[0];
}

// ---------------- K4: proj VALID conv fused with chunk-max + sum partials
// grid = 8 b * 256 e * 4 ltiles (1792 l each = 2 pool chunks of 896); 224 active thr.
__global__ __launch_bounds__(256) void k_proj(const float* __restrict__ X,
                                              const float* __restrict__ emb,
                                              float* __restrict__ psum,
                                              float* __restrict__ cmax) {
    __shared__ float xl[2816];
    __shared__ float el[1024];
    __shared__ float red[256];
    const int bi = blockIdx.x;
    const int b    = bi >> 10;
    const int e    = (bi >> 2) & 255;
    const int tile = bi & 3;
    const int tid  = threadIdx.x;
    const int lb = tile * 1792;
    const float* xb = X + b * LL;
    for (int k = tid; k < 2816; k += 256) {
        int g = lb + k;
        xl[k] = (g < LL) ? xb[g] : 0.f;
    }
    const float* er = emb + e * KK;
    for (int t = tid; t < KK; t += 256) el[t] = er[t];
    __syncthreads();

    float acc[8] = {0,0,0,0,0,0,0,0};
    const int mo = tid * 8;
    if (tid < 224) {
        int t = 0;
        for (; t + 8 <= KK; t += 8) {
#pragma unroll
            for (int tt = 0; tt < 8; ++tt) {
                float ev = el[t + tt];
#pragma unroll
                for (int i = 0; i < 8; ++i) acc[i] = fmaf(xl[mo + t + tt + i], ev, acc[i]);
            }
        }
        for (; t < KK; ++t) {
            float ev = el[t];
#pragma unroll
            for (int i = 0; i < 8; ++i) acc[i] = fmaf(xl[mo + t + i], ev, acc[i]);
        }
    }
    float s = 0.f, mx = NEG_INF;
    if (tid < 224) {
#pragma unroll
        for (int i = 0; i < 8; ++i) {
            int l = lb + mo + i;
            if (l < LO) { s += acc[i]; mx = fmaxf(mx, acc[i]); }
        }
    }
    // sum partial (for the row mean)
    red[tid] = s;
    __syncthreads();
    for (int off = 128; off; off >>= 1) {
        if (tid < off) red[tid] += red[tid + off];
        __syncthreads();
    }
    if (tid == 0) psum[(b * 256 + e) * 4 + tile] = red[0];
    __syncthreads();
    // chunk maxes: threads 0..111 -> chunk tile*2, 112..223 -> chunk tile*2+1
    red[tid] = NEG_INF;
    __syncthreads();
    if (tid < 224) { int ci = tid / 112, wi = tid % 112; red[ci * 128 + wi] = mx; }
    __syncthreads();
    for (int off = 64; off; off >>= 1) {
        if ((tid & 127) < off) red[tid] = fmaxf(red[tid], red[tid + off]);
        __syncthreads();
    }
    if (tid == 0)   cmax[(b * 256 + e) * 8 + tile * 2 + 0] = red[0];
    if (tid == 128) cmax[(b * 256 + e) * 8 + tile * 2 + 1] = red[128];
}

// ---------------- K5: combine pooling + LayerNorm over E ----------------
__global__ __launch_bounds__(256) void k_ln(const float* __restrict__ psum,
                                            const float* __restrict__ cmax,
                                            const float* __restrict__ ln_g,
                                            const float* __restrict__ ln_b,
                                            float* __restrict__ xn) {
    __shared__ float red[256];
    __shared__ float red2[256];
    const int bt = blockIdx.x;      // b*8 + t
    const int t = bt & 7;
    const int b = bt >> 3;
    const int e = threadIdx.x;
    const float* ps = psum + (b * 256 + e) * 4;
    float m = (ps[0] + ps[1] + ps[2] + ps[3]) * (1.0f / 7162.0f);
    const float* cm = cmax + (b * 256 + e) * 8;
    float v = (t < 7) ? cm[t] : fmaxf(cm[7], m);   // pad values all equal mean
    red[e] = v; red2[e] = v * v;
    __syncthreads();
    for (int off = 128; off; off >>= 1) {
        if (e < off) { red[e] += red[e + off]; red2[e] += red2[e + off]; }
        __syncthreads();
    }
    float mu  = red[0] * (1.0f / 256.0f);
    float var = red2[0] * (1.0f / 256.0f) - mu * mu;
    float r = 1.0f / sqrtf(var + 1e-5f);
    xn[bt * 256 + e] = (v - mu) * r * ln_g[e] + ln_b[e];
}

// ---------------- K6: FFN ----------------
__global__ __launch_bounds__(256) void k_ffn(const float* __restrict__ xn,
                                             const float* __restrict__ w1,
                                             const float* __restrict__ b1,
                                             const float* __restrict__ w2,
                                             const float* __restrict__ b2,
                                             float* __restrict__ hdd) {
    __shared__ float xr[256];
    __shared__ float h[512];
    const int bt = blockIdx.x;
    const int tid = threadIdx.x;
    xr[tid] = xn[bt * 256 + tid];
    __syncthreads();
    for (int jj = 0; jj < 2; ++jj) {
        int j = tid + jj * 256;
        float a = b1[j];
#pragma unroll 4
        for (int ee = 0; ee < 256; ++ee) a = fmaf(xr[ee], w1[ee * 512 + j], a);
        h[j] = fmaxf(a, 0.f);
    }
    __syncthreads();
    float a = b2[tid];
#pragma unroll 4
    for (int j = 0; j < 512; ++j) a = fmaf(h[j], w2[j * 256 + tid], a);
    hdd[bt * 256 + tid] = a;
}

// ---------------- K7: feat mean + classifier ----------------
__global__ void k_logits(const float* __restrict__ hdd,
                         const float* __restrict__ cls_w,
                         const float* __restrict__ cls_b,
                         float* __restrict__ out) {
    const int tid = threadIdx.x;
    if (tid < 80) {
        const int b = tid / 10, k = tid % 10;
        float a = cls_b[k];
        for (int e = 0; e < 256; ++e) {
            const float* hp = hdd + (b * 8) * 256 + e;
            float f = 0.f;
#pragma unroll
            for (int t = 0; t < 8; ++t) f += hp[t * 256];
            a = fmaf(f * 0.125f, cls_w[e * 10 + k], a);
        }
        out[tid] = a;
    }
}

// ---------------- K8: final scalar losses ----------------
__global__ __launch_bounds__(256) void k_losses(const float* __restrict__ recon_part,
                                                const float* __restrict__ vq_part,
                                                const int* __restrict__ hist,
                                                float* __restrict__ out) {
    __shared__ float red[256];
    const int tid = threadIdx.x;
    // recon: sum of 4096 block partials / (8*16*8184)
    float s = 0.f;
    for (int i = tid; i < 4096; i += 256) s += recon_part[i];
    red[tid] = s;
    __syncthreads();
    for (int off = 128; off; off >>= 1) { if (tid < off) red[tid] += red[tid + off]; __syncthreads(); }
    if (tid == 0) out[81] = red[0] / 1047552.0f;
    __syncthreads();
    // vq: 1.25 * mean((quant - Z)^2)
    red[tid] = (tid < 128) ? vq_part[tid] : 0.f;
    __syncthreads();
    for (int off = 128; off; off >>= 1) { if (tid < off) red[tid] += red[tid + off]; __syncthreads(); }
    if (tid == 0) out[80] = 1.25f * red[0] / 130944.0f;
    __syncthreads();
    // perplexity
    float avg = (float)hist[tid] * (1.0f / 128.0f);
    red[tid] = avg * logf(avg + EPSF);
    __syncthreads();
    for (int off = 128; off; off >>= 1) { if (tid < off) red[tid] += red[tid + off]; __syncthreads(); }
    if (tid == 0) out[82] = expf(-red[0]);
}

extern "C" void kernel_launch(void* const* d_in, const int* in_sizes, int n_in,
                              void* d_out, int out_size, void* d_ws, size_t ws_size,
                              hipStream_t stream) {
    const float* X     = (const float*)d_in[0];
    const float* emb   = (const float*)d_in[1];
    const float* w1    = (const float*)d_in[2];
    const float* b1    = (const float*)d_in[3];
    const float* w2    = (const float*)d_in[4];
    const float* b2    = (const float*)d_in[5];
    const float* ln_g  = (const float*)d_in[6];
    const float* ln_b  = (const float*)d_in[7];
    const float* cls_w = (const float*)d_in[8];
    const float* cls_b = (const float*)d_in[9];
    float* out = (float*)d_out;

    float* Z          = (float*)d_ws;          // 128*1023
    float* xnbuf      = Z + 130944;            // 64*256
    float* hdd        = xnbuf + 16384;         // 64*256
    float* psum       = hdd + 16384;           // 8*256*4
    float* cmaxb      = psum + 8192;           // 8*256*8
    float* recon_part = cmaxb + 16384;         // 4096
    float* vq_part    = recon_part + 4096;     // 128
    int*   codes      = (int*)(vq_part + 128); // 128
    int*   hist       = codes + 128;           // 256

    k_init<<<dim3(1), dim3(256), 0, stream>>>(hist);
    k_autocov<<<dim3(256), dim3(256), 0, stream>>>(X, Z);
    k_vq<<<dim3(128), dim3(256), 0, stream>>>(Z, emb, codes, hist, vq_part);
    k_conv_recon<<<dim3(4096), dim3(256), 0, stream>>>(X, emb, codes, recon_part);
    k_proj<<<dim3(8192), dim3(256), 0, stream>>>(X, emb, psum, cmaxb);
    k_ln<<<dim3(64), dim3(256), 0, stream>>>(psum, cmaxb, ln_g, ln_b, xnbuf);
    k_ffn<<<dim3(64), dim3(256), 0, stream>>>(xnbuf, w1, b1, w2, b2, hdd);
    k_logits<<<dim3(1), dim3(128), 0, stream>>>(hdd, cls_w, cls_b, out);
    k_losses<<<dim3(1), dim3(256), 0, stream>>>(recon_part, vq_part, hist, out);
}

// Round 2
// 1106.252 us; speedup vs baseline: 2.3545x; 2.3545x over previous
//
#include <hip/hip_runtime.h>

#define KK 1023
#define KPAD 1032
#define LL 8184
#define LO 7162
#define EPSF 1.1920928955078125e-07f
#define NEG_INF (-3.4028234663852886e+38f)

__device__ __constant__ int c_pos[16] = {0,409,818,1227,1636,2045,2454,2863,
                                         3273,3682,4091,4500,4909,5318,5727,6137};

// ---------------- K0: zero the code histogram ----------------
__global__ void k_init(int* __restrict__ hist) {
    hist[threadIdx.x] = 0;
}

// ---------------- K1: frames -> windowed/normalized -> circular autocorr -> Z
__global__ __launch_bounds__(256) void k_autocov(const float* __restrict__ X,
                                                 float* __restrict__ Z) {
    __shared__ float xw[2046];
    __shared__ float red[256];
    const int fi   = blockIdx.x >> 1;
    const int half = blockIdx.x & 1;
    const int b = fi >> 4, h = fi & 15;
    const int tid = threadIdx.x;
    const float* xp = X + b * LL + c_pos[h];

    float lmax = 0.f;
    for (int j = tid; j < KK; j += 256) {
        float v = xp[j];
        xw[j] = v;
        lmax = fmaxf(lmax, fabsf(v));
    }
    red[tid] = lmax;
    __syncthreads();
    for (int off = 128; off; off >>= 1) {
        if (tid < off) red[tid] = fmaxf(red[tid], red[tid + off]);
        __syncthreads();
    }
    float fmax = red[0];
    if (fmax == 0.f) fmax = EPSF;
    __syncthreads();
    for (int j = tid; j < KK; j += 256) {
        float v = xw[j];
        float win = 0.5f * (1.0f - cosf(6.28318530717958647692f * (float)j / 1023.0f));
        float w = v * win / fmax;
        xw[j] = w;
        xw[j + KK] = w;   // duplicate so c[m] = sum_j xw[j]*xw[j+m], no modulo
    }
    __syncthreads();

    const int m1 = half * 512 + tid;
    const int m2 = m1 + 256;
    float a0 = 0.f, a1 = 0.f;
#pragma unroll 8
    for (int j = 0; j < KK; ++j) {
        float xj = xw[j];
        a0 = fmaf(xj, xw[j + m1], a0);
        a1 = fmaf(xj, xw[j + m2], a1);
    }
    float* zrow = Z + fi * KK;
    int i1 = m1 + 512; if (i1 >= KK) i1 -= KK;   // Z[i] = c[(i+511)%1023]
    zrow[i1] = a0;
    if (m2 < KK) {
        int i2 = m2 + 512; if (i2 >= KK) i2 -= KK;
        zrow[i2] = a1;
    }
}

// ---------------- K2: VQ argmin + vq-loss partial + histogram ----------------
__global__ __launch_bounds__(256) void k_vq(const float* __restrict__ Z,
                                            const float* __restrict__ emb,
                                            int* __restrict__ codes,
                                            int* __restrict__ hist,
                                            float* __restrict__ vq_part) {
    __shared__ float zl[KK];
    __shared__ float rv[256];
    __shared__ int   ri[256];
    const int fi = blockIdx.x, tid = threadIdx.x;
    const float* zrow = Z + fi * KK;
    for (int t = tid; t < KK; t += 256) zl[t] = zrow[t];
    __syncthreads();

    // d'_e = ||e||^2 - 2 z.e (same argmin as full distance)
    const float* er = emb + tid * KK;
    float d = 0.f;
#pragma unroll 4
    for (int t = 0; t < KK; ++t) {
        float e = er[t];
        d = fmaf(e, e - 2.f * zl[t], d);
    }
    rv[tid] = d; ri[tid] = tid;
    __syncthreads();
    for (int off = 128; off; off >>= 1) {
        if (tid < off) {
            float v2 = rv[tid + off]; int i2 = ri[tid + off];
            if (v2 < rv[tid] || (v2 == rv[tid] && i2 < ri[tid])) { rv[tid] = v2; ri[tid] = i2; }
        }
        __syncthreads();
    }
    const int code = ri[0];
    if (tid == 0) { codes[fi] = code; atomicAdd(&hist[code], 1); }

    const float* qr = emb + code * KK;
    float s = 0.f;
    for (int t = tid; t < KK; t += 256) { float dd = qr[t] - zl[t]; s += dd * dd; }
    __syncthreads();
    rv[tid] = s;
    __syncthreads();
    for (int off = 128; off; off >>= 1) {
        if (tid < off) rv[tid] += rv[tid + off];
        __syncthreads();
    }
    if (tid == 0) vq_part[fi] = rv[0];
}

// ---------------- K2b: dedup codes (identical filters -> identical conv rows)
__global__ void k_dedup(const int* __restrict__ codes,
                        int* __restrict__ firstmap, int* __restrict__ mult) {
    __shared__ int c[128];
    const int f = threadIdx.x;
    c[f] = codes[f];
    __syncthreads();
    int first = f, cnt = 0;
    for (int j = 0; j < 128; ++j) {
        if (c[j] == c[f]) { if (j < first) first = j; ++cnt; }
    }
    firstmap[f] = first;
    mult[f] = cnt;
}

// 32 FMAs on a 12-float register window, taps 4n..4n+3
#define SUBG(Qv, Wa, Wb, Wc)                                                 \
    {                                                                        \
        float w[12] = {Wa.x, Wa.y, Wa.z, Wa.w, Wb.x, Wb.y, Wb.z, Wb.w,      \
                       Wc.x, Wc.y, Wc.z, Wc.w};                              \
        float qa[4] = {Qv.x, Qv.y, Qv.z, Qv.w};                              \
        _Pragma("unroll")                                                    \
        for (int tt = 0; tt < 4; ++tt) {                                     \
            _Pragma("unroll")                                                \
            for (int i = 0; i < 8; ++i)                                      \
                acc[i] = fmaf(qa[tt], w[tt + i], acc[i]);                    \
        }                                                                    \
    }

// ---------------- K3: big SAME conv fused with recon partial
// grid = 8 n * 128 f * 4 ltiles; 256 thr; 8 outputs/thread; register window.
__global__ __launch_bounds__(256) void k_conv_recon(const float* __restrict__ X,
                                                    const float* __restrict__ emb,
                                                    const int* __restrict__ codes,
                                                    const int* __restrict__ firstmap,
                                                    const int* __restrict__ mult,
                                                    float* __restrict__ recon_part) {
    __shared__ __align__(16) float xl[3080];
    __shared__ __align__(16) float ql[KPAD];
    __shared__ float red[256];
    const int bi = blockIdx.x;
    const int n    = bi >> 9;
    const int f    = (bi >> 2) & 127;
    const int tile = bi & 3;
    const int tid  = threadIdx.x;

    if (firstmap[f] != f) {            // duplicate filter: representative covers it
        if (tid == 0) recon_part[bi] = 0.f;
        return;
    }

    const int tbase = tile * 2048;
    const int gs = tbase - 511;                 // SAME pad 511
    const float* xrow = X + n * LL;
    for (int k = tid; k < 3080; k += 256) {
        int g = gs + k;
        xl[k] = (g >= 0 && g < LL) ? xrow[g] : 0.f;
    }
    const int code = codes[f];
    const float* qr = emb + code * KK;
    for (int t = tid; t < KPAD; t += 256) ql[t] = (t < KK) ? qr[t] : 0.f;
    __syncthreads();

    float acc[8] = {0,0,0,0,0,0,0,0};
    const int mo = tid * 8;
    const float4* xl4 = reinterpret_cast<const float4*>(xl) + (mo >> 2);
    const float4* ql4 = reinterpret_cast<const float4*>(ql);
    float4 A = xl4[0], B = xl4[1], C;
    for (int g = 0; g < 86; ++g) {
#pragma unroll
        for (int s = 0; s < 3; ++s) {
            const int nsub = 3 * g + s;
            C = xl4[2 + nsub];
            float4 Q = ql4[nsub];
            SUBG(Q, A, B, C);
            A = B; B = C;
        }
    }

    float s = 0.f;
#pragma unroll
    for (int i = 0; i < 8; ++i) {
        int l = tbase + mo + i;
        if (l < LL) {
            float d = acc[i] - xl[mo + i + 511];   // X[n,l]
            s += d * d;
        }
    }
    red[tid] = s;
    __syncthreads();
    for (int off = 128; off; off >>= 1) {
        if (tid < off) red[tid] += red[tid + off];
        __syncthreads();
    }
    if (tid == 0) recon_part[bi] = red[0] * (float)mult[f];
}

// ---------------- K4: proj VALID conv fused with chunk-max + sum partials
// grid = 8 b * 256 e * 4 ltiles (1792 l each = 2 pool chunks of 896); 224 active thr.
__global__ __launch_bounds__(256) void k_proj(const float* __restrict__ X,
                                              const float* __restrict__ emb,
                                              float* __restrict__ psum,
                                              float* __restrict__ cmax) {
    __shared__ __align__(16) float xl[2824];
    __shared__ __align__(16) float el[KPAD];
    __shared__ float red[256];
    const int bi = blockIdx.x;
    const int b    = bi >> 10;
    const int e    = (bi >> 2) & 255;
    const int tile = bi & 3;
    const int tid  = threadIdx.x;
    const int lb = tile * 1792;
    const float* xb = X + b * LL;
    for (int k = tid; k < 2824; k += 256) {
        int g = lb + k;
        xl[k] = (g < LL) ? xb[g] : 0.f;
    }
    const float* er = emb + e * KK;
    for (int t = tid; t < KPAD; t += 256) el[t] = (t < KK) ? er[t] : 0.f;
    __syncthreads();

    float acc[8] = {0,0,0,0,0,0,0,0};
    const int mo = tid * 8;
    float s = 0.f, mx = NEG_INF;
    if (tid < 224) {
        const float4* xl4 = reinterpret_cast<const float4*>(xl) + (mo >> 2);
        const float4* el4 = reinterpret_cast<const float4*>(el);
        float4 A = xl4[0], B = xl4[1], C;
        for (int g = 0; g < 86; ++g) {
#pragma unroll
            for (int ss = 0; ss < 3; ++ss) {
                const int nsub = 3 * g + ss;
                C = xl4[2 + nsub];
                float4 Q = el4[nsub];
                SUBG(Q, A, B, C);
                A = B; B = C;
            }
        }
#pragma unroll
        for (int i = 0; i < 8; ++i) {
            int l = lb + mo + i;
            if (l < LO) { s += acc[i]; mx = fmaxf(mx, acc[i]); }
        }
    }
    // sum partial (for the row mean)
    red[tid] = s;
    __syncthreads();
    for (int off = 128; off; off >>= 1) {
        if (tid < off) red[tid] += red[tid + off];
        __syncthreads();
    }
    if (tid == 0) psum[(b * 256 + e) * 4 + tile] = red[0];
    __syncthreads();
    // chunk maxes: threads 0..111 -> chunk tile*2, 112..223 -> chunk tile*2+1
    red[tid] = NEG_INF;
    __syncthreads();
    if (tid < 224) { int ci = tid / 112, wi = tid % 112; red[ci * 128 + wi] = mx; }
    __syncthreads();
    for (int off = 64; off; off >>= 1) {
        if ((tid & 127) < off) red[tid] = fmaxf(red[tid], red[tid + off]);
        __syncthreads();
    }
    if (tid == 0)   cmax[(b * 256 + e) * 8 + tile * 2 + 0] = red[0];
    if (tid == 128) cmax[(b * 256 + e) * 8 + tile * 2 + 1] = red[128];
}

// ---------------- K5: combine pooling + LayerNorm over E ----------------
__global__ __launch_bounds__(256) void k_ln(const float* __restrict__ psum,
                                            const float* __restrict__ cmax,
                                            const float* __restrict__ ln_g,
                                            const float* __restrict__ ln_b,
                                            float* __restrict__ xn) {
    __shared__ float red[256];
    __shared__ float red2[256];
    const int bt = blockIdx.x;      // b*8 + t
    const int t = bt & 7;
    const int b = bt >> 3;
    const int e = threadIdx.x;
    const float* ps = psum + (b * 256 + e) * 4;
    float m = (ps[0] + ps[1] + ps[2] + ps[3]) * (1.0f / 7162.0f);
    const float* cm = cmax + (b * 256 + e) * 8;
    float v = (t < 7) ? cm[t] : fmaxf(cm[7], m);   // pad values all equal mean
    red[e] = v; red2[e] = v * v;
    __syncthreads();
    for (int off = 128; off; off >>= 1) {
        if (e < off) { red[e] += red[e + off]; red2[e] += red2[e + off]; }
        __syncthreads();
    }
    float mu  = red[0] * (1.0f / 256.0f);
    float var = red2[0] * (1.0f / 256.0f) - mu * mu;
    float r = 1.0f / sqrtf(var + 1e-5f);
    xn[bt * 256 + e] = (v - mu) * r * ln_g[e] + ln_b[e];
}

// ---------------- K6: FFN ----------------
__global__ __launch_bounds__(256) void k_ffn(const float* __restrict__ xn,
                                             const float* __restrict__ w1,
                                             const float* __restrict__ b1,
                                             const float* __restrict__ w2,
                                             const float* __restrict__ b2,
                                             float* __restrict__ hdd) {
    __shared__ float xr[256];
    __shared__ float h[512];
    const int bt = blockIdx.x;
    const int tid = threadIdx.x;
    xr[tid] = xn[bt * 256 + tid];
    __syncthreads();
    for (int jj = 0; jj < 2; ++jj) {
        int j = tid + jj * 256;
        float a = b1[j];
#pragma unroll 4
        for (int ee = 0; ee < 256; ++ee) a = fmaf(xr[ee], w1[ee * 512 + j], a);
        h[j] = fmaxf(a, 0.f);
    }
    __syncthreads();
    float a = b2[tid];
#pragma unroll 4
    for (int j = 0; j < 512; ++j) a = fmaf(h[j], w2[j * 256 + tid], a);
    hdd[bt * 256 + tid] = a;
}

// ---------------- K7: feat mean + classifier ----------------
__global__ void k_logits(const float* __restrict__ hdd,
                         const float* __restrict__ cls_w,
                         const float* __restrict__ cls_b,
                         float* __restrict__ out) {
    const int tid = threadIdx.x;
    if (tid < 80) {
        const int b = tid / 10, k = tid % 10;
        float a = cls_b[k];
        for (int e = 0; e < 256; ++e) {
            const float* hp = hdd + (b * 8) * 256 + e;
            float f = 0.f;
#pragma unroll
            for (int t = 0; t < 8; ++t) f += hp[t * 256];
            a = fmaf(f * 0.125f, cls_w[e * 10 + k], a);
        }
        out[tid] = a;
    }
}

// ---------------- K8: final scalar losses ----------------
__global__ __launch_bounds__(256) void k_losses(const float* __restrict__ recon_part,
                                                const float* __restrict__ vq_part,
                                                const int* __restrict__ hist,
                                                float* __restrict__ out) {
    __shared__ float red[256];
    const int tid = threadIdx.x;
    // recon: sum of 4096 block partials / (8*16*8184)
    float s = 0.f;
    for (int i = tid; i < 4096; i += 256) s += recon_part[i];
    red[tid] = s;
    __syncthreads();
    for (int off = 128; off; off >>= 1) { if (tid < off) red[tid] += red[tid + off]; __syncthreads(); }
    if (tid == 0) out[81] = red[0] / 1047552.0f;
    __syncthreads();
    // vq: 1.25 * mean((quant - Z)^2)
    red[tid] = (tid < 128) ? vq_part[tid] : 0.f;
    __syncthreads();
    for (int off = 128; off; off >>= 1) { if (tid < off) red[tid] += red[tid + off]; __syncthreads(); }
    if (tid == 0) out[80] = 1.25f * red[0] / 130944.0f;
    __syncthreads();
    // perplexity
    float avg = (float)hist[tid] * (1.0f / 128.0f);
    red[tid] = avg * logf(avg + EPSF);
    __syncthreads();
    for (int off = 128; off; off >>= 1) { if (tid < off) red[tid] += red[tid + off]; __syncthreads(); }
    if (tid == 0) out[82] = expf(-red[0]);
}

extern "C" void kernel_launch(void* const* d_in, const int* in_sizes, int n_in,
                              void* d_out, int out_size, void* d_ws, size_t ws_size,
                              hipStream_t stream) {
    const float* X     = (const float*)d_in[0];
    const float* emb   = (const float*)d_in[1];
    const float* w1    = (const float*)d_in[2];
    const float* b1    = (const float*)d_in[3];
    const float* w2    = (const float*)d_in[4];
    const float* b2    = (const float*)d_in[5];
    const float* ln_g  = (const float*)d_in[6];
    const float* ln_b  = (const float*)d_in[7];
    const float* cls_w = (const float*)d_in[8];
    const float* cls_b = (const float*)d_in[9];
    float* out = (float*)d_out;

    float* Z          = (float*)d_ws;          // 128*1023
    float* xnbuf      = Z + 130944;            // 64*256
    float* hdd        = xnbuf + 16384;         // 64*256
    float* psum       = hdd + 16384;           // 8*256*4
    float* cmaxb      = psum + 8192;           // 8*256*8
    float* recon_part = cmaxb + 16384;         // 4096
    float* vq_part    = recon_part + 4096;     // 128
    int*   codes      = (int*)(vq_part + 128); // 128
    int*   hist       = codes + 128;           // 256
    int*   firstmap   = hist + 256;            // 128
    int*   multb      = firstmap + 128;        // 128

    k_init<<<dim3(1), dim3(256), 0, stream>>>(hist);
    k_autocov<<<dim3(256), dim3(256), 0, stream>>>(X, Z);
    k_vq<<<dim3(128), dim3(256), 0, stream>>>(Z, emb, codes, hist, vq_part);
    k_dedup<<<dim3(1), dim3(128), 0, stream>>>(codes, firstmap, multb);
    k_conv_recon<<<dim3(4096), dim3(256), 0, stream>>>(X, emb, codes, firstmap, multb, recon_part);
    k_proj<<<dim3(8192), dim3(256), 0, stream>>>(X, emb, psum, cmaxb);
    k_ln<<<dim3(64), dim3(256), 0, stream>>>(psum, cmaxb, ln_g, ln_b, xnbuf);
    k_ffn<<<dim3(64), dim3(256), 0, stream>>>(xnbuf, w1, b1, w2, b2, hdd);
    k_logits<<<dim3(1), dim3(128), 0, stream>>>(hdd, cls_w, cls_b, out);
    k_losses<<<dim3(1), dim3(256), 0, stream>>>(recon_part, vq_part, hist, out);
}

// Round 3
// 728.312 us; speedup vs baseline: 3.5763x; 1.5189x over previous
//
#include <hip/hip_runtime.h>

#define KK 1023
#define KPAD 1032
#define LL 8184
#define LO 7162
#define EPSF 1.1920928955078125e-07f
#define NEG_INF (-3.4028234663852886e+38f)

// LDS skew: float4 index j stored at j + (j>>3); word index k at k + ((k>>5)<<2).
// A wave's b128 reads at lane-stride 2 float4 then cover all 8 bank-groups
// uniformly (8 lanes each) -> conflict-free minimum 8 phases.
#define PHI4(j) ((j) + ((j) >> 3))
#define PSI(k)  ((k) + ((((k) >> 5)) << 2))

__device__ __constant__ int c_pos[16] = {0,409,818,1227,1636,2045,2454,2863,
                                         3273,3682,4091,4500,4909,5318,5727,6137};

// ---------------- K0: zero the code histogram ----------------
__global__ void k_init(int* __restrict__ hist) {
    hist[threadIdx.x] = 0;
}

// ---------------- K1: frames -> windowed/normalized -> circular autocorr -> Z
// 4 blocks per frame, 1 lag per thread.
__global__ __launch_bounds__(256) void k_autocov(const float* __restrict__ X,
                                                 float* __restrict__ Z) {
    __shared__ float xw[2046];
    __shared__ float red[256];
    const int fi   = blockIdx.x >> 2;
    const int quad = blockIdx.x & 3;
    const int b = fi >> 4, h = fi & 15;
    const int tid = threadIdx.x;
    const float* xp = X + b * LL + c_pos[h];

    float lmax = 0.f;
    for (int j = tid; j < KK; j += 256) {
        float v = xp[j];
        xw[j] = v;
        lmax = fmaxf(lmax, fabsf(v));
    }
    red[tid] = lmax;
    __syncthreads();
    for (int off = 128; off; off >>= 1) {
        if (tid < off) red[tid] = fmaxf(red[tid], red[tid + off]);
        __syncthreads();
    }
    float fmax = red[0];
    if (fmax == 0.f) fmax = EPSF;
    __syncthreads();
    for (int j = tid; j < KK; j += 256) {
        float v = xw[j];
        float win = 0.5f * (1.0f - cosf(6.28318530717958647692f * (float)j / 1023.0f));
        float w = v * win / fmax;
        xw[j] = w;
        xw[j + KK] = w;   // duplicate so c[m] = sum_j xw[j]*xw[j+m], no modulo
    }
    __syncthreads();

    const int m1 = quad * 256 + tid;
    if (m1 < KK) {
        float a0 = 0.f;
#pragma unroll 8
        for (int j = 0; j < KK; ++j) {
            a0 = fmaf(xw[j], xw[j + m1], a0);
        }
        float* zrow = Z + fi * KK;
        int i1 = m1 + 512; if (i1 >= KK) i1 -= KK;   // Z[i] = c[(i+511)%1023]
        zrow[i1] = a0;
    }
}

// ---------------- K2: VQ argmin + vq-loss partial + histogram ----------------
__global__ __launch_bounds__(256) void k_vq(const float* __restrict__ Z,
                                            const float* __restrict__ emb,
                                            int* __restrict__ codes,
                                            int* __restrict__ hist,
                                            float* __restrict__ vq_part) {
    __shared__ float zl[KK];
    __shared__ float rv[256];
    __shared__ int   ri[256];
    const int fi = blockIdx.x, tid = threadIdx.x;
    const float* zrow = Z + fi * KK;
    for (int t = tid; t < KK; t += 256) zl[t] = zrow[t];
    __syncthreads();

    // d'_e = ||e||^2 - 2 z.e (same argmin as full distance)
    const float* er = emb + tid * KK;
    float d = 0.f;
#pragma unroll 4
    for (int t = 0; t < KK; ++t) {
        float e = er[t];
        d = fmaf(e, e - 2.f * zl[t], d);
    }
    rv[tid] = d; ri[tid] = tid;
    __syncthreads();
    for (int off = 128; off; off >>= 1) {
        if (tid < off) {
            float v2 = rv[tid + off]; int i2 = ri[tid + off];
            if (v2 < rv[tid] || (v2 == rv[tid] && i2 < ri[tid])) { rv[tid] = v2; ri[tid] = i2; }
        }
        __syncthreads();
    }
    const int code = ri[0];
    if (tid == 0) { codes[fi] = code; atomicAdd(&hist[code], 1); }

    const float* qr = emb + code * KK;
    float s = 0.f;
    for (int t = tid; t < KK; t += 256) { float dd = qr[t] - zl[t]; s += dd * dd; }
    __syncthreads();
    rv[tid] = s;
    __syncthreads();
    for (int off = 128; off; off >>= 1) {
        if (tid < off) rv[tid] += rv[tid + off];
        __syncthreads();
    }
    if (tid == 0) vq_part[fi] = rv[0];
}

// ---------------- K2b: dedup codes (identical filters -> identical conv rows)
__global__ void k_dedup(const int* __restrict__ codes,
                        int* __restrict__ firstmap, int* __restrict__ mult) {
    __shared__ int c[128];
    const int f = threadIdx.x;
    c[f] = codes[f];
    __syncthreads();
    int first = f, cnt = 0;
    for (int j = 0; j < 128; ++j) {
        if (c[j] == c[f]) { if (j < first) first = j; ++cnt; }
    }
    firstmap[f] = first;
    mult[f] = cnt;
}

// 32 FMAs on a 12-float register window, taps 4n..4n+3
#define SUBG(Qv, Wa, Wb, Wc)                                                 \
    {                                                                        \
        float w[12] = {Wa.x, Wa.y, Wa.z, Wa.w, Wb.x, Wb.y, Wb.z, Wb.w,      \
                       Wc.x, Wc.y, Wc.z, Wc.w};                              \
        float qa[4] = {Qv.x, Qv.y, Qv.z, Qv.w};                              \
        _Pragma("unroll")                                                    \
        for (int tt = 0; tt < 4; ++tt) {                                     \
            _Pragma("unroll")                                                \
            for (int i = 0; i < 8; ++i)                                      \
                acc[i] = fmaf(qa[tt], w[tt + i], acc[i]);                    \
        }                                                                    \
    }

// ---------------- K3: big SAME conv fused with recon partial
// grid = 8 n * 128 f * 4 ltiles; 256 thr; 8 outputs/thread; skewed LDS window.
__global__ __launch_bounds__(256) void k_conv_recon(const float* __restrict__ X,
                                                    const float* __restrict__ emb,
                                                    const int* __restrict__ codes,
                                                    const int* __restrict__ firstmap,
                                                    const int* __restrict__ mult,
                                                    float* __restrict__ recon_part) {
    __shared__ __align__(16) float xl[3472];
    __shared__ __align__(16) float ql[KPAD];
    __shared__ float red[256];
    const int bi = blockIdx.x;
    const int n    = bi >> 9;
    const int f    = (bi >> 2) & 127;
    const int tile = bi & 3;
    const int tid  = threadIdx.x;

    if (firstmap[f] != f) {            // duplicate filter: representative covers it
        if (tid == 0) recon_part[bi] = 0.f;
        return;
    }

    const int tbase = tile * 2048;
    const int gs = tbase - 511;                 // SAME pad 511
    const float* xrow = X + n * LL;
    for (int k = tid; k < 3088; k += 256) {
        int g = gs + k;
        xl[PSI(k)] = (g >= 0 && g < LL) ? xrow[g] : 0.f;
    }
    const int code = codes[f];
    const float* qr = emb + code * KK;
    for (int t = tid; t < KPAD; t += 256) ql[t] = (t < KK) ? qr[t] : 0.f;
    __syncthreads();

    float acc[8] = {0,0,0,0,0,0,0,0};
    const int mo = tid * 8;
    const int j0 = tid * 2;
    const float4* xl4 = reinterpret_cast<const float4*>(xl);
    const float4* ql4 = reinterpret_cast<const float4*>(ql);
    float4 A = xl4[PHI4(j0)], B = xl4[PHI4(j0 + 1)], C;
    for (int g = 0; g < 86; ++g) {
#pragma unroll
        for (int s = 0; s < 3; ++s) {
            const int nsub = 3 * g + s;
            C = xl4[PHI4(j0 + 2 + nsub)];
            float4 Q = ql4[nsub];
            SUBG(Q, A, B, C);
            A = B; B = C;
        }
    }

    float s = 0.f;
#pragma unroll
    for (int i = 0; i < 8; ++i) {
        int l = tbase + mo + i;
        if (l < LL) {
            float d = acc[i] - xl[PSI(mo + i + 511)];   // X[n,l]
            s += d * d;
        }
    }
    red[tid] = s;
    __syncthreads();
    for (int off = 128; off; off >>= 1) {
        if (tid < off) red[tid] += red[tid + off];
        __syncthreads();
    }
    if (tid == 0) recon_part[bi] = red[0] * (float)mult[f];
}

// ---------------- K4: proj VALID conv fused with chunk-max + sum partials
// grid = 8 b * 256 e * 4 ltiles (1792 l each = 2 pool chunks of 896); 224 active thr.
__global__ __launch_bounds__(256) void k_proj(const float* __restrict__ X,
                                              const float* __restrict__ emb,
                                              float* __restrict__ psum,
                                              float* __restrict__ cmax) {
    __shared__ __align__(16) float xl[3184];
    __shared__ __align__(16) float el[KPAD];
    __shared__ float red[256];
    const int bi = blockIdx.x;
    const int b    = bi >> 10;
    const int e    = (bi >> 2) & 255;
    const int tile = bi & 3;
    const int tid  = threadIdx.x;
    const int lb = tile * 1792;
    const float* xb = X + b * LL;
    for (int k = tid; k < 2824; k += 256) {
        int g = lb + k;
        xl[PSI(k)] = (g < LL) ? xb[g] : 0.f;
    }
    const float* er = emb + e * KK;
    for (int t = tid; t < KPAD; t += 256) el[t] = (t < KK) ? er[t] : 0.f;
    __syncthreads();

    float acc[8] = {0,0,0,0,0,0,0,0};
    const int mo = tid * 8;
    float s = 0.f, mx = NEG_INF;
    if (tid < 224) {
        const int j0 = tid * 2;
        const float4* xl4 = reinterpret_cast<const float4*>(xl);
        const float4* el4 = reinterpret_cast<const float4*>(el);
        float4 A = xl4[PHI4(j0)], B = xl4[PHI4(j0 + 1)], C;
        for (int g = 0; g < 86; ++g) {
#pragma unroll
            for (int ss = 0; ss < 3; ++ss) {
                const int nsub = 3 * g + ss;
                C = xl4[PHI4(j0 + 2 + nsub)];
                float4 Q = el4[nsub];
                SUBG(Q, A, B, C);
                A = B; B = C;
            }
        }
#pragma unroll
        for (int i = 0; i < 8; ++i) {
            int l = lb + mo + i;
            if (l < LO) { s += acc[i]; mx = fmaxf(mx, acc[i]); }
        }
    }
    // sum partial (for the row mean)
    red[tid] = s;
    __syncthreads();
    for (int off = 128; off; off >>= 1) {
        if (tid < off) red[tid] += red[tid + off];
        __syncthreads();
    }
    if (tid == 0) psum[(b * 256 + e) * 4 + tile] = red[0];
    __syncthreads();
    // chunk maxes: threads 0..111 -> chunk tile*2, 112..223 -> chunk tile*2+1
    red[tid] = NEG_INF;
    __syncthreads();
    if (tid < 224) { int ci = tid / 112, wi = tid % 112; red[ci * 128 + wi] = mx; }
    __syncthreads();
    for (int off = 64; off; off >>= 1) {
        if ((tid & 127) < off) red[tid] = fmaxf(red[tid], red[tid + off]);
        __syncthreads();
    }
    if (tid == 0)   cmax[(b * 256 + e) * 8 + tile * 2 + 0] = red[0];
    if (tid == 128) cmax[(b * 256 + e) * 8 + tile * 2 + 1] = red[128];
}

// ---------------- K5: combine pooling + LayerNorm over E ----------------
__global__ __launch_bounds__(256) void k_ln(const float* __restrict__ psum,
                                            const float* __restrict__ cmax,
                                            const float* __restrict__ ln_g,
                                            const float* __restrict__ ln_b,
                                            float* __restrict__ xn) {
    __shared__ float red[256];
    __shared__ float red2[256];
    const int bt = blockIdx.x;      // b*8 + t
    const int t = bt & 7;
    const int b = bt >> 3;
    const int e = threadIdx.x;
    const float* ps = psum + (b * 256 + e) * 4;
    float m = (ps[0] + ps[1] + ps[2] + ps[3]) * (1.0f / 7162.0f);
    const float* cm = cmax + (b * 256 + e) * 8;
    float v = (t < 7) ? cm[t] : fmaxf(cm[7], m);   // pad values all equal mean
    red[e] = v; red2[e] = v * v;
    __syncthreads();
    for (int off = 128; off; off >>= 1) {
        if (e < off) { red[e] += red[e + off]; red2[e] += red2[e + off]; }
        __syncthreads();
    }
    float mu  = red[0] * (1.0f / 256.0f);
    float var = red2[0] * (1.0f / 256.0f) - mu * mu;
    float r = 1.0f / sqrtf(var + 1e-5f);
    xn[bt * 256 + e] = (v - mu) * r * ln_g[e] + ln_b[e];
}

// ---------------- K6: FFN ----------------
__global__ __launch_bounds__(256) void k_ffn(const float* __restrict__ xn,
                                             const float* __restrict__ w1,
                                             const float* __restrict__ b1,
                                             const float* __restrict__ w2,
                                             const float* __restrict__ b2,
                                             float* __restrict__ hdd) {
    __shared__ float xr[256];
    __shared__ float h[512];
    const int bt = blockIdx.x;
    const int tid = threadIdx.x;
    xr[tid] = xn[bt * 256 + tid];
    __syncthreads();
    for (int jj = 0; jj < 2; ++jj) {
        int j = tid + jj * 256;
        float a = b1[j];
#pragma unroll 4
        for (int ee = 0; ee < 256; ++ee) a = fmaf(xr[ee], w1[ee * 512 + j], a);
        h[j] = fmaxf(a, 0.f);
    }
    __syncthreads();
    float a = b2[tid];
#pragma unroll 4
    for (int j = 0; j < 512; ++j) a = fmaf(h[j], w2[j * 256 + tid], a);
    hdd[bt * 256 + tid] = a;
}

// ---------------- K7: feat mean + classifier ----------------
__global__ void k_logits(const float* __restrict__ hdd,
                         const float* __restrict__ cls_w,
                         const float* __restrict__ cls_b,
                         float* __restrict__ out) {
    const int tid = threadIdx.x;
    if (tid < 80) {
        const int b = tid / 10, k = tid % 10;
        float a = cls_b[k];
        for (int e = 0; e < 256; ++e) {
            const float* hp = hdd + (b * 8) * 256 + e;
            float f = 0.f;
#pragma unroll
            for (int t = 0; t < 8; ++t) f += hp[t * 256];
            a = fmaf(f * 0.125f, cls_w[e * 10 + k], a);
        }
        out[tid] = a;
    }
}

// ---------------- K8: final scalar losses ----------------
__global__ __launch_bounds__(256) void k_losses(const float* __restrict__ recon_part,
                                                const float* __restrict__ vq_part,
                                                const int* __restrict__ hist,
                                                float* __restrict__ out) {
    __shared__ float red[256];
    const int tid = threadIdx.x;
    // recon: sum of 4096 block partials / (8*16*8184)
    float s = 0.f;
    for (int i = tid; i < 4096; i += 256) s += recon_part[i];
    red[tid] = s;
    __syncthreads();
    for (int off = 128; off; off >>= 1) { if (tid < off) red[tid] += red[tid + off]; __syncthreads(); }
    if (tid == 0) out[81] = red[0] / 1047552.0f;
    __syncthreads();
    // vq: 1.25 * mean((quant - Z)^2)
    red[tid] = (tid < 128) ? vq_part[tid] : 0.f;
    __syncthreads();
    for (int off = 128; off; off >>= 1) { if (tid < off) red[tid] += red[tid + off]; __syncthreads(); }
    if (tid == 0) out[80] = 1.25f * red[0] / 130944.0f;
    __syncthreads();
    // perplexity
    float avg = (float)hist[tid] * (1.0f / 128.0f);
    red[tid] = avg * logf(avg + EPSF);
    __syncthreads();
    for (int off = 128; off; off >>= 1) { if (tid < off) red[tid] += red[tid + off]; __syncthreads(); }
    if (tid == 0) out[82] = expf(-red[0]);
}

extern "C" void kernel_launch(void* const* d_in, const int* in_sizes, int n_in,
                              void* d_out, int out_size, void* d_ws, size_t ws_size,
                              hipStream_t stream) {
    const float* X     = (const float*)d_in[0];
    const float* emb   = (const float*)d_in[1];
    const float* w1    = (const float*)d_in[2];
    const float* b1    = (const float*)d_in[3];
    const float* w2    = (const float*)d_in[4];
    const float* b2    = (const float*)d_in[5];
    const float* ln_g  = (const float*)d_in[6];
    const float* ln_b  = (const float*)d_in[7];
    const float* cls_w = (const float*)d_in[8];
    const float* cls_b = (const float*)d_in[9];
    float* out = (float*)d_out;

    float* Z          = (float*)d_ws;          // 128*1023
    float* xnbuf      = Z + 130944;            // 64*256
    float* hdd        = xnbuf + 16384;         // 64*256
    float* psum       = hdd + 16384;           // 8*256*4
    float* cmaxb      = psum + 8192;           // 8*256*8
    float* recon_part = cmaxb + 16384;         // 4096
    float* vq_part    = recon_part + 4096;     // 128
    int*   codes      = (int*)(vq_part + 128); // 128
    int*   hist       = codes + 128;           // 256
    int*   firstmap   = hist + 256;            // 128
    int*   multb      = firstmap + 128;        // 128

    k_init<<<dim3(1), dim3(256), 0, stream>>>(hist);
    k_autocov<<<dim3(512), dim3(256), 0, stream>>>(X, Z);
    k_vq<<<dim3(128), dim3(256), 0, stream>>>(Z, emb, codes, hist, vq_part);
    k_dedup<<<dim3(1), dim3(128), 0, stream>>>(codes, firstmap, multb);
    k_conv_recon<<<dim3(4096), dim3(256), 0, stream>>>(X, emb, codes, firstmap, multb, recon_part);
    k_proj<<<dim3(8192), dim3(256), 0, stream>>>(X, emb, psum, cmaxb);
    k_ln<<<dim3(64), dim3(256), 0, stream>>>(psum, cmaxb, ln_g, ln_b, xnbuf);
    k_ffn<<<dim3(64), dim3(256), 0, stream>>>(xnbuf, w1, b1, w2, b2, hdd);
    k_logits<<<dim3(1), dim3(128), 0, stream>>>(hdd, cls_w, cls_b, out);
    k_losses<<<dim3(1), dim3(256), 0, stream>>>(recon_part, vq_part, hist, out);
}

// Round 5
// 258.355 us; speedup vs baseline: 10.0816x; 2.8190x over previous
//
#include <hip/hip_runtime.h>

#define KK 1023
#define LL 8184
#define LO 7162
#define XPS 10240
#define EPSF 1.1920928955078125e-07f
#define NEG_INF (-3.4028234663852886e+38f)

typedef short bf16x8 __attribute__((ext_vector_type(8)));
typedef float f32x4 __attribute__((ext_vector_type(4)));

__device__ __constant__ int c_pos[16] = {0,409,818,1227,1636,2045,2454,2863,
                                         3273,3682,4091,4500,4909,5318,5727,6137};

__device__ __forceinline__ unsigned short f2bf(float f) {
    unsigned u = __float_as_uint(f);
    unsigned r = (u + 0x7FFFu + ((u >> 16) & 1u)) >> 16;
    return (unsigned short)r;
}
__device__ __forceinline__ int fenc(float f) {
    int u = __float_as_int(f);
    return u >= 0 ? u : (~u) ^ 0x80000000;
}
__device__ __forceinline__ float fdec(int k) {
    int u = k >= 0 ? k : ~(k ^ 0x80000000);
    return __int_as_float(u);
}
__device__ __forceinline__ void gl2lds16(const void* g, void* l) {
    __builtin_amdgcn_global_load_lds(
        (const __attribute__((address_space(1))) void*)g,
        (__attribute__((address_space(3))) void*)l, 16, 0, 0);
}

// ---------------- K0: init hist + cmax ----------------
__global__ void k_init(int* __restrict__ hist, int* __restrict__ cmax) {
    int i = blockIdx.x * 256 + threadIdx.x;
    cmax[i] = INT_MIN;                 // grid 64*256 = 16384 = cmax size
    if (i < 256) hist[i] = 0;
}

// ---------------- prep: X -> padded bf16 rows (and +1-shifted copy) ----------
__global__ __launch_bounds__(256) void k_prep_x(const float* __restrict__ X,
                                                unsigned short* __restrict__ Xpad,
                                                unsigned short* __restrict__ Xodd) {
    const int b = blockIdx.x >> 2, seg = blockIdx.x & 3;
    for (int i = seg * 2560 + threadIdx.x; i < (seg + 1) * 2560; i += 256) {
        unsigned short v = 0, vo = 0;
        if (i >= 512 && i < 512 + LL) v = f2bf(X[b * LL + (i - 512)]);
        const int i1 = i + 1;
        if (i1 >= 512 && i1 < 512 + LL) vo = f2bf(X[b * LL + (i1 - 512)]);
        Xpad[b * XPS + i] = v;
        Xodd[b * XPS + i] = vo;        // Xodd[i] = Xpad[i+1]
    }
}

// ---------------- prep: emb -> bf16 [256][1024] ----------------
__global__ __launch_bounds__(256) void k_prep_e(const float* __restrict__ emb,
                                                unsigned short* __restrict__ Ebf) {
    const int e = blockIdx.x;
    for (int k = threadIdx.x; k < 1024; k += 256)
        Ebf[e * 1024 + k] = (k < KK) ? f2bf(emb[e * KK + k]) : (unsigned short)0;
}

// ---------------- K1: autocov (2 lags/thread, float2 register window) --------
__global__ __launch_bounds__(256) void k_autocov(const float* __restrict__ X,
                                                 float* __restrict__ Z) {
    __shared__ __align__(16) float xw[2046];
    __shared__ float red[256];
    const int fi = blockIdx.x >> 1, half = blockIdx.x & 1;
    const int b = fi >> 4, h = fi & 15;
    const int tid = threadIdx.x;
    const float* xp = X + b * LL + c_pos[h];

    float lmax = 0.f;
    for (int j = tid; j < KK; j += 256) {
        float v = xp[j];
        xw[j] = v;
        lmax = fmaxf(lmax, fabsf(v));
    }
    red[tid] = lmax;
    __syncthreads();
    for (int off = 128; off; off >>= 1) {
        if (tid < off) red[tid] = fmaxf(red[tid], red[tid + off]);
        __syncthreads();
    }
    float fmx = red[0];
    if (fmx == 0.f) fmx = EPSF;
    __syncthreads();
    for (int j = tid; j < KK; j += 256) {
        float v = xw[j];
        float win = 0.5f * (1.0f - cosf(6.28318530717958647692f * (float)j / 1023.0f));
        float w = v * win / fmx;
        xw[j] = w;
        xw[j + KK] = w;        // duplicate: c[m] = sum_j xw[j]*xw[j+m], no modulo
    }
    __syncthreads();

    const int m2 = half * 512 + 2 * tid;
    const int mh = m2 >> 1;
    const float2* X2 = (const float2*)xw;
    float a0 = 0.f, a1 = 0.f;
    float2 F = X2[mh];
#pragma unroll 4
    for (int jh = 0; jh < 511; ++jh) {
        float2 xj = X2[jh];                 // uniform broadcast
        float2 G = X2[mh + jh + 1];
        a0 = fmaf(xj.x, F.x, a0);
        a0 = fmaf(xj.y, F.y, a0);
        a1 = fmaf(xj.x, F.y, a1);
        a1 = fmaf(xj.y, G.x, a1);
        F = G;
    }
    float xt = xw[1022];
    a0 = fmaf(xt, F.x, a0);
    a1 = fmaf(xt, F.y, a1);
    float* zrow = Z + fi * KK;
    int i0 = m2 + 512; if (i0 >= KK) i0 -= KK;   // Z[i] = c[(i+511)%1023]
    zrow[i0] = a0;
    if (m2 + 1 < KK) {
        int i1 = m2 + 513; if (i1 >= KK) i1 -= KK;
        zrow[i1] = a1;
    }
}

// ---------------- K2: VQ argmin + vq-loss partial + histogram ----------------
__global__ __launch_bounds__(256) void k_vq(const float* __restrict__ Z,
                                            const float* __restrict__ emb,
                                            int* __restrict__ codes,
                                            int* __restrict__ hist,
                                            float* __restrict__ vq_part) {
    __shared__ float zl[KK];
    __shared__ float rv[256];
    __shared__ int   ri[256];
    const int fi = blockIdx.x, tid = threadIdx.x;
    const float* zrow = Z + fi * KK;
    for (int t = tid; t < KK; t += 256) zl[t] = zrow[t];
    __syncthreads();

    const float* er = emb + tid * KK;
    float d = 0.f;
#pragma unroll 4
    for (int t = 0; t < KK; ++t) {
        float e = er[t];
        d = fmaf(e, e - 2.f * zl[t], d);
    }
    rv[tid] = d; ri[tid] = tid;
    __syncthreads();
    for (int off = 128; off; off >>= 1) {
        if (tid < off) {
            float v2 = rv[tid + off]; int i2 = ri[tid + off];
            if (v2 < rv[tid] || (v2 == rv[tid] && i2 < ri[tid])) { rv[tid] = v2; ri[tid] = i2; }
        }
        __syncthreads();
    }
    const int code = ri[0];
    if (tid == 0) { codes[fi] = code; atomicAdd(&hist[code], 1); }

    const float* qr = emb + code * KK;
    float s = 0.f;
    for (int t = tid; t < KK; t += 256) { float dd = qr[t] - zl[t]; s += dd * dd; }
    __syncthreads();
    rv[tid] = s;
    __syncthreads();
    for (int off = 128; off; off >>= 1) {
        if (tid < off) rv[tid] += rv[tid + off];
        __syncthreads();
    }
    if (tid == 0) vq_part[fi] = rv[0];
}

// ---------------- K3: merged MFMA implicit-GEMM, FULL N coverage ----------------
// grid 768: [0,512) proj (b, ehalf, l0/256), [512,768) recon (b, l0/256).
// Block: 512 thr / 8 waves = (we: M-half 64) x (wg: nt-quad).
// l = l0 + nt + 16*c via 16 pre-shifted LDS windows W_nt[i] = Xpad[l0+nt+i].
__global__ __launch_bounds__(512, 2) void k_gemm(const unsigned short* __restrict__ Xpad,
                                                 const unsigned short* __restrict__ Xodd,
                                                 const unsigned short* __restrict__ Ebf,
                                                 const int* __restrict__ codes,
                                                 const float* __restrict__ X,
                                                 float* __restrict__ psum_part,
                                                 float* __restrict__ recon_part,
                                                 int* __restrict__ cmax) {
    __shared__ __align__(16) unsigned short lds_b[16 * 1536];  // 49152 B: 16 windows
    __shared__ __align__(16) unsigned short lds_a[2 * 4096];   // 16384 B: A dbuf [128][32]
    __shared__ float red_s[2][64][4];
    const int tid  = threadIdx.x;
    const int lane = tid & 63;
    const int c = lane & 15, g = lane >> 4;
    const int w = tid >> 6, we = w & 1, wg = w >> 1;

    const int bi = blockIdx.x;
    const bool isproj = bi < 512;
    int b, l0, e0;
    if (isproj) { b = bi >> 6; int r = bi & 63; e0 = (r >> 5) * 128; l0 = (r & 31) * 256; }
    else        { int q = bi - 512; b = q >> 5; e0 = 0; l0 = (q & 31) * 256; }
    const int xw0 = (isproj ? 512 : 0) + l0;

    // ---- stage 16 B-windows: wave w stages windows 2w, 2w+1 (3 passes of 64x16B)
    {
        const unsigned short* base_e = Xpad + b * XPS;
        const unsigned short* base_o = Xodd + b * XPS;
#pragma unroll
        for (int kk = 0; kk < 2; ++kk) {
            const int wdw = 2 * w + kk;
            const unsigned short* src = (wdw & 1) ? (base_o + xw0 + wdw - 1)
                                                  : (base_e + xw0 + wdw);
#pragma unroll
            for (int p = 0; p < 3; ++p)
                gl2lds16(src + p * 512 + lane * 8, lds_b + wdw * 1536 + p * 512 + lane * 8);
        }
    }
    // ---- stage A step 0: thread t -> row t>>2, quarter t&3
    const int r_lds = tid >> 2, q4 = tid & 3;
    const int grow = isproj ? (e0 + r_lds) : codes[r_lds];
    const unsigned short* e_src = Ebf + grow * 1024 + q4 * 8;
    gl2lds16(e_src, lds_a + tid * 8);
    __syncthreads();

    f32x4 acc[4][4];
#pragma unroll
    for (int i = 0; i < 4; ++i)
#pragma unroll
        for (int j = 0; j < 4; ++j) acc[i][j] = (f32x4){0.f, 0.f, 0.f, 0.f};

    const char* lax = (const char*)lds_a;
    const char* lbx = (const char*)lds_b;
    const int boff0 = (wg * 4) * 3072 + 32 * c + 16 * g;
    const int aoff0 = we * 4096 + c * 64 + g * 16;

    for (int s = 0; s < 32; ++s) {
        const int cur = s & 1;
        if (s + 1 < 32)
            gl2lds16(e_src + (s + 1) * 32, lds_a + ((s + 1) & 1) * 4096 + tid * 8);
        const char* ab = lax + cur * 8192 + aoff0;
        bf16x8 af[4];
#pragma unroll
        for (int et = 0; et < 4; ++et) af[et] = *(const bf16x8*)(ab + et * 1024);
#pragma unroll
        for (int ntl = 0; ntl < 4; ++ntl) {
            bf16x8 bfrag = *(const bf16x8*)(lbx + boff0 + ntl * 3072 + 64 * s);
#pragma unroll
            for (int et = 0; et < 4; ++et)
                acc[et][ntl] = __builtin_amdgcn_mfma_f32_16x16x32_bf16(af[et], bfrag, acc[et][ntl], 0, 0, 0);
        }
        __syncthreads();
    }

    const int lseg  = l0 >> 8;
    const int lbase = l0 + wg * 4;         // l = lbase + ntl + 16*c
    if (isproj) {
        const int ch0 = lbase / 896;
#pragma unroll
        for (int et = 0; et < 4; ++et) {
#pragma unroll
            for (int r = 0; r < 4; ++r) {
                float ssum = 0.f, m0 = NEG_INF, m1 = NEG_INF;
#pragma unroll
                for (int ntl = 0; ntl < 4; ++ntl) {
                    float v = acc[et][ntl][r];
                    int l = lbase + ntl + 16 * c;
                    bool ok = l < LO;
                    ssum += ok ? v : 0.f;
                    int ch = l / 896;
                    if (ok && ch == ch0) m0 = fmaxf(m0, v);
                    if (ok && ch != ch0) m1 = fmaxf(m1, v);
                }
                ssum += __shfl_xor(ssum, 1); ssum += __shfl_xor(ssum, 2);
                ssum += __shfl_xor(ssum, 4); ssum += __shfl_xor(ssum, 8);
                m0 = fmaxf(m0, __shfl_xor(m0, 1)); m0 = fmaxf(m0, __shfl_xor(m0, 2));
                m0 = fmaxf(m0, __shfl_xor(m0, 4)); m0 = fmaxf(m0, __shfl_xor(m0, 8));
                m1 = fmaxf(m1, __shfl_xor(m1, 1)); m1 = fmaxf(m1, __shfl_xor(m1, 2));
                m1 = fmaxf(m1, __shfl_xor(m1, 4)); m1 = fmaxf(m1, __shfl_xor(m1, 8));
                if (c == 0) {
                    int eidx = et * 16 + g * 4 + r;
                    red_s[we][eidx][wg] = ssum;
                    int e = e0 + we * 64 + eidx;
                    int cb = (b * 256 + e) * 8;
                    if (m0 > NEG_INF && ch0 < 8)     atomicMax(&cmax[cb + ch0], fenc(m0));
                    if (m1 > NEG_INF && ch0 + 1 < 8) atomicMax(&cmax[cb + ch0 + 1], fenc(m1));
                }
            }
        }
    } else {
        float xv[4];
#pragma unroll
        for (int ntl = 0; ntl < 4; ++ntl) {
            int lr = lbase + ntl + 16 * c - 1;
            xv[ntl] = (lr >= 0 && lr < LL) ? X[b * LL + lr] : 0.f;
        }
#pragma unroll
        for (int et = 0; et < 4; ++et) {
#pragma unroll
            for (int r = 0; r < 4; ++r) {
                float ssum = 0.f;
#pragma unroll
                for (int ntl = 0; ntl < 4; ++ntl) {
                    int lr = lbase + ntl + 16 * c - 1;
                    bool ok = (lr >= 0) && (lr < LL);
                    float dd = ok ? (acc[et][ntl][r] - xv[ntl]) : 0.f;
                    ssum += dd * dd;
                }
                ssum += __shfl_xor(ssum, 1); ssum += __shfl_xor(ssum, 2);
                ssum += __shfl_xor(ssum, 4); ssum += __shfl_xor(ssum, 8);
                if (c == 0) red_s[we][et * 16 + g * 4 + r][wg] = ssum;
            }
        }
    }
    __syncthreads();
    if (tid < 128) {
        const int wwe = tid >> 6, eidx = tid & 63;
        float tot = red_s[wwe][eidx][0] + red_s[wwe][eidx][1]
                  + red_s[wwe][eidx][2] + red_s[wwe][eidx][3];
        if (isproj) {
            int e = e0 + wwe * 64 + eidx;
            psum_part[(b * 256 + e) * 32 + lseg] = tot;
        } else {
            int f = wwe * 64 + eidx;
            recon_part[(b * 128 + f) * 32 + lseg] = tot;
        }
    }
}

// ---------------- K5: combine pooling + LayerNorm over E ----------------
__global__ __launch_bounds__(256) void k_ln(const float* __restrict__ psum_part,
                                            const int* __restrict__ cmax,
                                            const float* __restrict__ ln_g,
                                            const float* __restrict__ ln_b,
                                            float* __restrict__ xn) {
    __shared__ float red[256];
    __shared__ float red2[256];
    const int bt = blockIdx.x;      // b*8 + t
    const int t = bt & 7;
    const int b = bt >> 3;
    const int e = threadIdx.x;
    const float* ps = psum_part + ((b * 256 + e) << 5);
    float sm = 0.f;
#pragma unroll
    for (int s = 0; s < 32; ++s) sm += ps[s];
    float m = sm * (1.0f / 7162.0f);
    const int cb = (b * 256 + e) << 3;
    float v = (t < 7) ? fdec(cmax[cb + t]) : fmaxf(fdec(cmax[cb + 7]), m);
    red[e] = v; red2[e] = v * v;
    __syncthreads();
    for (int off = 128; off; off >>= 1) {
        if (e < off) { red[e] += red[e + off]; red2[e] += red2[e + off]; }
        __syncthreads();
    }
    float mu  = red[0] * (1.0f / 256.0f);
    float var = red2[0] * (1.0f / 256.0f) - mu * mu;
    float r = 1.0f / sqrtf(var + 1e-5f);
    xn[bt * 256 + e] = (v - mu) * r * ln_g[e] + ln_b[e];
}

// ---------------- K6: FFN ----------------
__global__ __launch_bounds__(256) void k_ffn(const float* __restrict__ xn,
                                             const float* __restrict__ w1,
                                             const float* __restrict__ b1,
                                             const float* __restrict__ w2,
                                             const float* __restrict__ b2,
                                             float* __restrict__ hdd) {
    __shared__ float xr[256];
    __shared__ float h[512];
    const int bt = blockIdx.x;
    const int tid = threadIdx.x;
    xr[tid] = xn[bt * 256 + tid];
    __syncthreads();
    for (int jj = 0; jj < 2; ++jj) {
        int j = tid + jj * 256;
        float a = b1[j];
#pragma unroll 4
        for (int ee = 0; ee < 256; ++ee) a = fmaf(xr[ee], w1[ee * 512 + j], a);
        h[j] = fmaxf(a, 0.f);
    }
    __syncthreads();
    float a = b2[tid];
#pragma unroll 4
    for (int j = 0; j < 512; ++j) a = fmaf(h[j], w2[j * 256 + tid], a);
    hdd[bt * 256 + tid] = a;
}

// ---------------- K7: feat mean + classifier ----------------
__global__ void k_logits(const float* __restrict__ hdd,
                         const float* __restrict__ cls_w,
                         const float* __restrict__ cls_b,
                         float* __restrict__ out) {
    const int tid = threadIdx.x;
    if (tid < 80) {
        const int b = tid / 10, k = tid % 10;
        float a = cls_b[k];
        for (int e = 0; e < 256; ++e) {
            const float* hp = hdd + (b * 8) * 256 + e;
            float f = 0.f;
#pragma unroll
            for (int t = 0; t < 8; ++t) f += hp[t * 256];
            a = fmaf(f * 0.125f, cls_w[e * 10 + k], a);
        }
        out[tid] = a;
    }
}

// ---------------- K8: final scalar losses ----------------
__global__ __launch_bounds__(256) void k_losses(const float* __restrict__ recon_part,
                                                const float* __restrict__ vq_part,
                                                const int* __restrict__ hist,
                                                float* __restrict__ out) {
    __shared__ float red[256];
    const int tid = threadIdx.x;
    float s = 0.f;
    for (int i = tid; i < 32768; i += 256) s += recon_part[i];
    red[tid] = s;
    __syncthreads();
    for (int off = 128; off; off >>= 1) { if (tid < off) red[tid] += red[tid + off]; __syncthreads(); }
    if (tid == 0) out[81] = red[0] / 1047552.0f;
    __syncthreads();
    red[tid] = (tid < 128) ? vq_part[tid] : 0.f;
    __syncthreads();
    for (int off = 128; off; off >>= 1) { if (tid < off) red[tid] += red[tid + off]; __syncthreads(); }
    if (tid == 0) out[80] = 1.25f * red[0] / 130944.0f;
    __syncthreads();
    float avg = (float)hist[tid] * (1.0f / 128.0f);
    red[tid] = avg * logf(avg + EPSF);
    __syncthreads();
    for (int off = 128; off; off >>= 1) { if (tid < off) red[tid] += red[tid + off]; __syncthreads(); }
    if (tid == 0) out[82] = expf(-red[0]);
}

extern "C" void kernel_launch(void* const* d_in, const int* in_sizes, int n_in,
                              void* d_out, int out_size, void* d_ws, size_t ws_size,
                              hipStream_t stream) {
    const float* X     = (const float*)d_in[0];
    const float* emb   = (const float*)d_in[1];
    const float* w1    = (const float*)d_in[2];
    const float* b1    = (const float*)d_in[3];
    const float* w2    = (const float*)d_in[4];
    const float* b2    = (const float*)d_in[5];
    const float* ln_g  = (const float*)d_in[6];
    const float* ln_b  = (const float*)d_in[7];
    const float* cls_w = (const float*)d_in[8];
    const float* cls_b = (const float*)d_in[9];
    float* out = (float*)d_out;

    float* Z            = (float*)d_ws;            // 130944
    float* vq_part      = Z + 130944;              // 128
    float* xnbuf        = vq_part + 128;           // 16384
    float* hdd          = xnbuf + 16384;           // 16384
    float* psum_part    = hdd + 16384;             // 65536
    float* recon_part   = psum_part + 65536;       // 32768
    int*   cmaxb        = (int*)(recon_part + 32768);  // 16384
    int*   codes        = cmaxb + 16384;           // 128
    int*   hist         = codes + 128;             // 256
    unsigned short* Xpad = (unsigned short*)(hist + 256);   // 8*10240 shorts
    unsigned short* Xodd = Xpad + 8 * XPS;                  // 8*10240 shorts
    unsigned short* Ebf  = Xodd + 8 * XPS;                  // 256*1024 shorts

    k_init   <<<dim3(64),  dim3(256), 0, stream>>>(hist, cmaxb);
    k_prep_x <<<dim3(32),  dim3(256), 0, stream>>>(X, Xpad, Xodd);
    k_prep_e <<<dim3(256), dim3(256), 0, stream>>>(emb, Ebf);
    k_autocov<<<dim3(256), dim3(256), 0, stream>>>(X, Z);
    k_vq     <<<dim3(128), dim3(256), 0, stream>>>(Z, emb, codes, hist, vq_part);
    k_gemm   <<<dim3(768), dim3(512), 0, stream>>>(Xpad, Xodd, Ebf, codes, X, psum_part, recon_part, cmaxb);
    k_ln     <<<dim3(64),  dim3(256), 0, stream>>>(psum_part, cmaxb, ln_g, ln_b, xnbuf);
    k_ffn    <<<dim3(64),  dim3(256), 0, stream>>>(xnbuf, w1, b1, w2, b2, hdd);
    k_logits <<<dim3(1),   dim3(128), 0, stream>>>(hdd, cls_w, cls_b, out);
    k_losses <<<dim3(1),   dim3(256), 0, stream>>>(recon_part, vq_part, hist, out);
}

// Round 6
// 196.651 us; speedup vs baseline: 13.2449x; 1.3138x over previous
//
#include <hip/hip_runtime.h>

#define KK 1023
#define LL 8184
#define LO 7162
#define XPS 10240
#define EPSF 1.1920928955078125e-07f
#define NEG_INF (-3.4028234663852886e+38f)

typedef short bf16x8 __attribute__((ext_vector_type(8)));
typedef float f32x4 __attribute__((ext_vector_type(4)));

__device__ __constant__ int c_pos[16] = {0,409,818,1227,1636,2045,2454,2863,
                                         3273,3682,4091,4500,4909,5318,5727,6137};

__device__ __forceinline__ unsigned short f2bf(float f) {
    unsigned u = __float_as_uint(f);
    unsigned r = (u + 0x7FFFu + ((u >> 16) & 1u)) >> 16;
    return (unsigned short)r;
}
__device__ __forceinline__ int fenc(float f) {
    int u = __float_as_int(f);
    return u >= 0 ? u : (~u) ^ 0x80000000;
}
__device__ __forceinline__ float fdec(int k) {
    int u = k >= 0 ? k : ~(k ^ 0x80000000);
    return __int_as_float(u);
}
__device__ __forceinline__ void gl2lds16(const void* g, void* l) {
    __builtin_amdgcn_global_load_lds(
        (const __attribute__((address_space(1))) void*)g,
        (__attribute__((address_space(3))) void*)l, 16, 0, 0);
}

// ---------------- K0: init hist + cmax ----------------
__global__ void k_init(int* __restrict__ hist, int* __restrict__ cmax) {
    int i = blockIdx.x * 256 + threadIdx.x;
    cmax[i] = INT_MIN;                 // grid 64*256 = 16384 = cmax size
    if (i < 256) hist[i] = 0;
}

// ---------------- prep: X -> padded bf16 rows (and +1-shifted copy) ----------
__global__ __launch_bounds__(256) void k_prep_x(const float* __restrict__ X,
                                                unsigned short* __restrict__ Xpad,
                                                unsigned short* __restrict__ Xodd) {
    const int b = blockIdx.x >> 2, seg = blockIdx.x & 3;
    for (int i = seg * 2560 + threadIdx.x; i < (seg + 1) * 2560; i += 256) {
        unsigned short v = 0, vo = 0;
        if (i >= 512 && i < 512 + LL) v = f2bf(X[b * LL + (i - 512)]);
        const int i1 = i + 1;
        if (i1 >= 512 && i1 < 512 + LL) vo = f2bf(X[b * LL + (i1 - 512)]);
        Xpad[b * XPS + i] = v;
        Xodd[b * XPS + i] = vo;        // Xodd[i] = Xpad[i+1]
    }
}

// ---------------- prep: emb -> bf16 [256][1024], f32 transpose Et4, enorm ----
__global__ __launch_bounds__(256) void k_prep_e(const float* __restrict__ emb,
                                                unsigned short* __restrict__ Ebf,
                                                float* __restrict__ Etf,
                                                float* __restrict__ enorm) {
    __shared__ float red[256];
    const int e = blockIdx.x;
    const int tid = threadIdx.x;
    const float* er = emb + e * KK;
    float nrm = 0.f;
    for (int k = tid; k < 1024; k += 256) {
        float v = (k < KK) ? er[k] : 0.f;
        Ebf[e * 1024 + k] = (k < KK) ? f2bf(v) : (unsigned short)0;
        // Et4 layout: float4 at [t4*256 + e]; float index = t4*1024 + e*4 + comp
        Etf[(k >> 2) * 1024 + e * 4 + (k & 3)] = v;
        nrm = fmaf(v, v, nrm);
    }
    red[tid] = nrm;
    __syncthreads();
    for (int off = 128; off; off >>= 1) {
        if (tid < off) red[tid] += red[tid + off];
        __syncthreads();
    }
    if (tid == 0) enorm[e] = red[0];
}

// ---------------- K1: autocov (2 lags/thread, float2 register window) --------
__global__ __launch_bounds__(256) void k_autocov(const float* __restrict__ X,
                                                 float* __restrict__ Z) {
    __shared__ __align__(16) float xw[2046];
    __shared__ float red[256];
    const int fi = blockIdx.x >> 1, half = blockIdx.x & 1;
    const int b = fi >> 4, h = fi & 15;
    const int tid = threadIdx.x;
    const float* xp = X + b * LL + c_pos[h];

    float lmax = 0.f;
    for (int j = tid; j < KK; j += 256) {
        float v = xp[j];
        xw[j] = v;
        lmax = fmaxf(lmax, fabsf(v));
    }
    red[tid] = lmax;
    __syncthreads();
    for (int off = 128; off; off >>= 1) {
        if (tid < off) red[tid] = fmaxf(red[tid], red[tid + off]);
        __syncthreads();
    }
    float fmx = red[0];
    if (fmx == 0.f) fmx = EPSF;
    __syncthreads();
    for (int j = tid; j < KK; j += 256) {
        float v = xw[j];
        float win = 0.5f * (1.0f - cosf(6.28318530717958647692f * (float)j / 1023.0f));
        float w = v * win / fmx;
        xw[j] = w;
        xw[j + KK] = w;        // duplicate: c[m] = sum_j xw[j]*xw[j+m], no modulo
    }
    __syncthreads();

    const int m2 = half * 512 + 2 * tid;
    const int mh = m2 >> 1;
    const float2* X2 = (const float2*)xw;
    float a0 = 0.f, a1 = 0.f;
    float2 F = X2[mh];
#pragma unroll 4
    for (int jh = 0; jh < 511; ++jh) {
        float2 xj = X2[jh];                 // uniform broadcast
        float2 G = X2[mh + jh + 1];
        a0 = fmaf(xj.x, F.x, a0);
        a0 = fmaf(xj.y, F.y, a0);
        a1 = fmaf(xj.x, F.y, a1);
        a1 = fmaf(xj.y, G.x, a1);
        F = G;
    }
    float xt = xw[1022];
    a0 = fmaf(xt, F.x, a0);
    a1 = fmaf(xt, F.y, a1);
    float* zrow = Z + fi * KK;
    int i0 = m2 + 512; if (i0 >= KK) i0 -= KK;   // Z[i] = c[(i+511)%1023]
    zrow[i0] = a0;
    if (m2 + 1 < KK) {
        int i1 = m2 + 513; if (i1 >= KK) i1 -= KK;
        zrow[i1] = a1;
    }
}

// ---------------- K2: VQ argmin + vq-loss partial + histogram ----------------
// Phase 1 uses transposed Et4 (coalesced float4 per lane) + enorm.
__global__ __launch_bounds__(256) void k_vq(const float* __restrict__ Z,
                                            const float4* __restrict__ Et4,
                                            const float* __restrict__ enorm,
                                            const float* __restrict__ emb,
                                            int* __restrict__ codes,
                                            int* __restrict__ hist,
                                            float* __restrict__ vq_part) {
    __shared__ float zl[KK];
    __shared__ __align__(16) float zm2[1024];
    __shared__ float rv[256];
    __shared__ int   ri[256];
    const int fi = blockIdx.x, tid = threadIdx.x;
    const float* zrow = Z + fi * KK;
    for (int t = tid; t < 1024; t += 256) {
        float z = (t < KK) ? zrow[t] : 0.f;
        if (t < KK) zl[t] = z;
        zm2[t] = -2.f * z;
    }
    __syncthreads();

    float d = enorm[tid];
    const float4* zp = (const float4*)zm2;
    const float4* ep = Et4 + tid;
#pragma unroll 8
    for (int t4 = 0; t4 < 256; ++t4) {
        float4 ev = ep[t4 * 256];     // coalesced: lane stride 16B
        float4 zv = zp[t4];           // LDS broadcast
        d = fmaf(zv.x, ev.x, d);
        d = fmaf(zv.y, ev.y, d);
        d = fmaf(zv.z, ev.z, d);
        d = fmaf(zv.w, ev.w, d);
    }
    rv[tid] = d; ri[tid] = tid;
    __syncthreads();
    for (int off = 128; off; off >>= 1) {
        if (tid < off) {
            float v2 = rv[tid + off]; int i2 = ri[tid + off];
            if (v2 < rv[tid] || (v2 == rv[tid] && i2 < ri[tid])) { rv[tid] = v2; ri[tid] = i2; }
        }
        __syncthreads();
    }
    const int code = ri[0];
    if (tid == 0) { codes[fi] = code; atomicAdd(&hist[code], 1); }

    const float* qr = emb + code * KK;
    float s = 0.f;
    for (int t = tid; t < KK; t += 256) { float dd = qr[t] - zl[t]; s += dd * dd; }
    __syncthreads();
    rv[tid] = s;
    __syncthreads();
    for (int off = 128; off; off >>= 1) {
        if (tid < off) rv[tid] += rv[tid + off];
        __syncthreads();
    }
    if (tid == 0) vq_part[fi] = rv[0];
}

// ---------------- K3: merged MFMA implicit-GEMM, FULL N coverage ----------------
// grid 768: [0,512) proj (b, ehalf, l0/256), [512,768) recon (b, l0/256).
// Block: 512 thr / 8 waves = (we: M-half 64) x (wg: nt-quad).
// l = l0 + nt + 16*c via 16 pre-shifted LDS windows W_nt[i] = Xpad[l0+nt+i].
__global__ __launch_bounds__(512, 2) void k_gemm(const unsigned short* __restrict__ Xpad,
                                                 const unsigned short* __restrict__ Xodd,
                                                 const unsigned short* __restrict__ Ebf,
                                                 const int* __restrict__ codes,
                                                 const float* __restrict__ X,
                                                 float* __restrict__ psum_part,
                                                 float* __restrict__ recon_part,
                                                 int* __restrict__ cmax) {
    __shared__ __align__(16) unsigned short lds_b[16 * 1536];  // 49152 B: 16 windows
    __shared__ __align__(16) unsigned short lds_a[2 * 4096];   // 16384 B: A dbuf [128][32]
    __shared__ float red_s[2][64][4];
    const int tid  = threadIdx.x;
    const int lane = tid & 63;
    const int c = lane & 15, g = lane >> 4;
    const int w = tid >> 6, we = w & 1, wg = w >> 1;

    const int bi = blockIdx.x;
    const bool isproj = bi < 512;
    int b, l0, e0;
    if (isproj) { b = bi >> 6; int r = bi & 63; e0 = (r >> 5) * 128; l0 = (r & 31) * 256; }
    else        { int q = bi - 512; b = q >> 5; e0 = 0; l0 = (q & 31) * 256; }
    const int xw0 = (isproj ? 512 : 0) + l0;

    // ---- stage 16 B-windows: wave w stages windows 2w, 2w+1 (3 passes of 64x16B)
    {
        const unsigned short* base_e = Xpad + b * XPS;
        const unsigned short* base_o = Xodd + b * XPS;
#pragma unroll
        for (int kk = 0; kk < 2; ++kk) {
            const int wdw = 2 * w + kk;
            const unsigned short* src = (wdw & 1) ? (base_o + xw0 + wdw - 1)
                                                  : (base_e + xw0 + wdw);
#pragma unroll
            for (int p = 0; p < 3; ++p)
                gl2lds16(src + p * 512 + lane * 8, lds_b + wdw * 1536 + p * 512 + lane * 8);
        }
    }
    // ---- stage A step 0: thread t -> row t>>2, quarter t&3
    const int r_lds = tid >> 2, q4 = tid & 3;
    const int grow = isproj ? (e0 + r_lds) : codes[r_lds];
    const unsigned short* e_src = Ebf + grow * 1024 + q4 * 8;
    gl2lds16(e_src, lds_a + tid * 8);
    __syncthreads();

    f32x4 acc[4][4];
#pragma unroll
    for (int i = 0; i < 4; ++i)
#pragma unroll
        for (int j = 0; j < 4; ++j) acc[i][j] = (f32x4){0.f, 0.f, 0.f, 0.f};

    const char* lax = (const char*)lds_a;
    const char* lbx = (const char*)lds_b;
    const int boff0 = (wg * 4) * 3072 + 32 * c + 16 * g;
    const int aoff0 = we * 4096 + c * 64 + g * 16;

    for (int s = 0; s < 32; ++s) {
        const int cur = s & 1;
        if (s + 1 < 32)
            gl2lds16(e_src + (s + 1) * 32, lds_a + ((s + 1) & 1) * 4096 + tid * 8);
        const char* ab = lax + cur * 8192 + aoff0;
        bf16x8 af[4];
#pragma unroll
        for (int et = 0; et < 4; ++et) af[et] = *(const bf16x8*)(ab + et * 1024);
#pragma unroll
        for (int ntl = 0; ntl < 4; ++ntl) {
            bf16x8 bfrag = *(const bf16x8*)(lbx + boff0 + ntl * 3072 + 64 * s);
#pragma unroll
            for (int et = 0; et < 4; ++et)
                acc[et][ntl] = __builtin_amdgcn_mfma_f32_16x16x32_bf16(af[et], bfrag, acc[et][ntl], 0, 0, 0);
        }
        __syncthreads();
    }

    const int lseg  = l0 >> 8;
    const int lbase = l0 + wg * 4;         // l = lbase + ntl + 16*c
    if (isproj) {
        const int ch0 = lbase / 896;
#pragma unroll
        for (int et = 0; et < 4; ++et) {
#pragma unroll
            for (int r = 0; r < 4; ++r) {
                float ssum = 0.f, m0 = NEG_INF, m1 = NEG_INF;
#pragma unroll
                for (int ntl = 0; ntl < 4; ++ntl) {
                    float v = acc[et][ntl][r];
                    int l = lbase + ntl + 16 * c;
                    bool ok = l < LO;
                    ssum += ok ? v : 0.f;
                    int ch = l / 896;
                    if (ok && ch == ch0) m0 = fmaxf(m0, v);
                    if (ok && ch != ch0) m1 = fmaxf(m1, v);
                }
                ssum += __shfl_xor(ssum, 1); ssum += __shfl_xor(ssum, 2);
                ssum += __shfl_xor(ssum, 4); ssum += __shfl_xor(ssum, 8);
                m0 = fmaxf(m0, __shfl_xor(m0, 1)); m0 = fmaxf(m0, __shfl_xor(m0, 2));
                m0 = fmaxf(m0, __shfl_xor(m0, 4)); m0 = fmaxf(m0, __shfl_xor(m0, 8));
                m1 = fmaxf(m1, __shfl_xor(m1, 1)); m1 = fmaxf(m1, __shfl_xor(m1, 2));
                m1 = fmaxf(m1, __shfl_xor(m1, 4)); m1 = fmaxf(m1, __shfl_xor(m1, 8));
                if (c == 0) {
                    int eidx = et * 16 + g * 4 + r;
                    red_s[we][eidx][wg] = ssum;
                    int e = e0 + we * 64 + eidx;
                    int cb = (b * 256 + e) * 8;
                    if (m0 > NEG_INF && ch0 < 8)     atomicMax(&cmax[cb + ch0], fenc(m0));
                    if (m1 > NEG_INF && ch0 + 1 < 8) atomicMax(&cmax[cb + ch0 + 1], fenc(m1));
                }
            }
        }
    } else {
        float xv[4];
#pragma unroll
        for (int ntl = 0; ntl < 4; ++ntl) {
            int lr = lbase + ntl + 16 * c - 1;
            xv[ntl] = (lr >= 0 && lr < LL) ? X[b * LL + lr] : 0.f;
        }
#pragma unroll
        for (int et = 0; et < 4; ++et) {
#pragma unroll
            for (int r = 0; r < 4; ++r) {
                float ssum = 0.f;
#pragma unroll
                for (int ntl = 0; ntl < 4; ++ntl) {
                    int lr = lbase + ntl + 16 * c - 1;
                    bool ok = (lr >= 0) && (lr < LL);
                    float dd = ok ? (acc[et][ntl][r] - xv[ntl]) : 0.f;
                    ssum += dd * dd;
                }
                ssum += __shfl_xor(ssum, 1); ssum += __shfl_xor(ssum, 2);
                ssum += __shfl_xor(ssum, 4); ssum += __shfl_xor(ssum, 8);
                if (c == 0) red_s[we][et * 16 + g * 4 + r][wg] = ssum;
            }
        }
    }
    __syncthreads();
    if (tid < 128) {
        const int wwe = tid >> 6, eidx = tid & 63;
        float tot = red_s[wwe][eidx][0] + red_s[wwe][eidx][1]
                  + red_s[wwe][eidx][2] + red_s[wwe][eidx][3];
        if (isproj) {
            int e = e0 + wwe * 64 + eidx;
            psum_part[(b * 256 + e) * 32 + lseg] = tot;
        } else {
            int f = wwe * 64 + eidx;
            recon_part[(b * 128 + f) * 32 + lseg] = tot;
        }
    }
}

// ---------------- K5: combine pooling + LayerNorm over E ----------------
__global__ __launch_bounds__(256) void k_ln(const float* __restrict__ psum_part,
                                            const int* __restrict__ cmax,
                                            const float* __restrict__ ln_g,
                                            const float* __restrict__ ln_b,
                                            float* __restrict__ xn) {
    __shared__ float red[256];
    __shared__ float red2[256];
    const int bt = blockIdx.x;      // b*8 + t
    const int t = bt & 7;
    const int b = bt >> 3;
    const int e = threadIdx.x;
    const float* ps = psum_part + ((b * 256 + e) << 5);
    float sm = 0.f;
#pragma unroll
    for (int s = 0; s < 32; ++s) sm += ps[s];
    float m = sm * (1.0f / 7162.0f);
    const int cb = (b * 256 + e) << 3;
    float v = (t < 7) ? fdec(cmax[cb + t]) : fmaxf(fdec(cmax[cb + 7]), m);
    red[e] = v; red2[e] = v * v;
    __syncthreads();
    for (int off = 128; off; off >>= 1) {
        if (e < off) { red[e] += red[e + off]; red2[e] += red2[e + off]; }
        __syncthreads();
    }
    float mu  = red[0] * (1.0f / 256.0f);
    float var = red2[0] * (1.0f / 256.0f) - mu * mu;
    float r = 1.0f / sqrtf(var + 1e-5f);
    xn[bt * 256 + e] = (v - mu) * r * ln_g[e] + ln_b[e];
}

// ---------------- K6: FFN ----------------
__global__ __launch_bounds__(256) void k_ffn(const float* __restrict__ xn,
                                             const float* __restrict__ w1,
                                             const float* __restrict__ b1,
                                             const float* __restrict__ w2,
                                             const float* __restrict__ b2,
                                             float* __restrict__ hdd) {
    __shared__ float xr[256];
    __shared__ float h[512];
    const int bt = blockIdx.x;
    const int tid = threadIdx.x;
    xr[tid] = xn[bt * 256 + tid];
    __syncthreads();
    for (int jj = 0; jj < 2; ++jj) {
        int j = tid + jj * 256;
        float a = b1[j];
#pragma unroll 4
        for (int ee = 0; ee < 256; ++ee) a = fmaf(xr[ee], w1[ee * 512 + j], a);
        h[j] = fmaxf(a, 0.f);
    }
    __syncthreads();
    float a = b2[tid];
#pragma unroll 4
    for (int j = 0; j < 512; ++j) a = fmaf(h[j], w2[j * 256 + tid], a);
    hdd[bt * 256 + tid] = a;
}

// ---------------- K7: feat mean + classifier ----------------
__global__ void k_logits(const float* __restrict__ hdd,
                         const float* __restrict__ cls_w,
                         const float* __restrict__ cls_b,
                         float* __restrict__ out) {
    const int tid = threadIdx.x;
    if (tid < 80) {
        const int b = tid / 10, k = tid % 10;
        float a = cls_b[k];
        for (int e = 0; e < 256; ++e) {
            const float* hp = hdd + (b * 8) * 256 + e;
            float f = 0.f;
#pragma unroll
            for (int t = 0; t < 8; ++t) f += hp[t * 256];
            a = fmaf(f * 0.125f, cls_w[e * 10 + k], a);
        }
        out[tid] = a;
    }
}

// ---------------- K8: final scalar losses ----------------
__global__ __launch_bounds__(256) void k_losses(const float* __restrict__ recon_part,
                                                const float* __restrict__ vq_part,
                                                const int* __restrict__ hist,
                                                float* __restrict__ out) {
    __shared__ float red[256];
    const int tid = threadIdx.x;
    float s = 0.f;
    for (int i = tid; i < 32768; i += 256) s += recon_part[i];
    red[tid] = s;
    __syncthreads();
    for (int off = 128; off; off >>= 1) { if (tid < off) red[tid] += red[tid + off]; __syncthreads(); }
    if (tid == 0) out[81] = red[0] / 1047552.0f;
    __syncthreads();
    red[tid] = (tid < 128) ? vq_part[tid] : 0.f;
    __syncthreads();
    for (int off = 128; off; off >>= 1) { if (tid < off) red[tid] += red[tid + off]; __syncthreads(); }
    if (tid == 0) out[80] = 1.25f * red[0] / 130944.0f;
    __syncthreads();
    float avg = (float)hist[tid] * (1.0f / 128.0f);
    red[tid] = avg * logf(avg + EPSF);
    __syncthreads();
    for (int off = 128; off; off >>= 1) { if (tid < off) red[tid] += red[tid + off]; __syncthreads(); }
    if (tid == 0) out[82] = expf(-red[0]);
}

extern "C" void kernel_launch(void* const* d_in, const int* in_sizes, int n_in,
                              void* d_out, int out_size, void* d_ws, size_t ws_size,
                              hipStream_t stream) {
    const float* X     = (const float*)d_in[0];
    const float* emb   = (const float*)d_in[1];
    const float* w1    = (const float*)d_in[2];
    const float* b1    = (const float*)d_in[3];
    const float* w2    = (const float*)d_in[4];
    const float* b2    = (const float*)d_in[5];
    const float* ln_g  = (const float*)d_in[6];
    const float* ln_b  = (const float*)d_in[7];
    const float* cls_w = (const float*)d_in[8];
    const float* cls_b = (const float*)d_in[9];
    float* out = (float*)d_out;

    float* Z            = (float*)d_ws;            // 130944
    float* vq_part      = Z + 130944;              // 128
    float* xnbuf        = vq_part + 128;           // 16384
    float* hdd          = xnbuf + 16384;           // 16384
    float* psum_part    = hdd + 16384;             // 65536
    float* recon_part   = psum_part + 65536;       // 32768
    int*   cmaxb        = (int*)(recon_part + 32768);  // 16384
    int*   codes        = cmaxb + 16384;           // 128
    int*   hist         = codes + 128;             // 256
    unsigned short* Xpad = (unsigned short*)(hist + 256);   // 8*10240 shorts
    unsigned short* Xodd = Xpad + 8 * XPS;                  // 8*10240 shorts
    unsigned short* Ebf  = Xodd + 8 * XPS;                  // 256*1024 shorts
    float* Etf           = (float*)(Ebf + 256 * 1024);      // 256*1024 floats (Et4)
    float* enorm         = Etf + 256 * 1024;                // 256

    k_init   <<<dim3(64),  dim3(256), 0, stream>>>(hist, cmaxb);
    k_prep_x <<<dim3(32),  dim3(256), 0, stream>>>(X, Xpad, Xodd);
    k_prep_e <<<dim3(256), dim3(256), 0, stream>>>(emb, Ebf, Etf, enorm);
    k_autocov<<<dim3(256), dim3(256), 0, stream>>>(X, Z);
    k_vq     <<<dim3(128), dim3(256), 0, stream>>>(Z, (const float4*)Etf, enorm, emb, codes, hist, vq_part);
    k_gemm   <<<dim3(768), dim3(512), 0, stream>>>(Xpad, Xodd, Ebf, codes, X, psum_part, recon_part, cmaxb);
    k_ln     <<<dim3(64),  dim3(256), 0, stream>>>(psum_part, cmaxb, ln_g, ln_b, xnbuf);
    k_ffn    <<<dim3(64),  dim3(256), 0, stream>>>(xnbuf, w1, b1, w2, b2, hdd);
    k_logits <<<dim3(1),   dim3(128), 0, stream>>>(hdd, cls_w, cls_b, out);
    k_losses <<<dim3(1),   dim3(256), 0, stream>>>(recon_part, vq_part, hist, out);
}

// Round 7
// 145.377 us; speedup vs baseline: 17.9164x; 1.3527x over previous
//
#include <hip/hip_runtime.h>

#define KK 1023
#define LL 8184
#define LO 7162
#define XPS 10240
#define EPSF 1.1920928955078125e-07f
#define NEG_INF (-3.4028234663852886e+38f)

typedef short bf16x8 __attribute__((ext_vector_type(8)));
typedef float f32x4 __attribute__((ext_vector_type(4)));

__device__ __constant__ int c_pos[16] = {0,409,818,1227,1636,2045,2454,2863,
                                         3273,3682,4091,4500,4909,5318,5727,6137};

__device__ __forceinline__ unsigned short f2bf(float f) {
    unsigned u = __float_as_uint(f);
    unsigned r = (u + 0x7FFFu + ((u >> 16) & 1u)) >> 16;
    return (unsigned short)r;
}
__device__ __forceinline__ int fenc(float f) {
    int u = __float_as_int(f);
    return u >= 0 ? u : (~u) ^ 0x80000000;
}
__device__ __forceinline__ float fdec(int k) {
    int u = k >= 0 ? k : ~(k ^ 0x80000000);
    return __int_as_float(u);
}
__device__ __forceinline__ void gl2lds16(const void* g, void* l) {
    __builtin_amdgcn_global_load_lds(
        (const __attribute__((address_space(1))) void*)g,
        (__attribute__((address_space(3))) void*)l, 16, 0, 0);
}

// ---------------- K0: merged prep: X->bf16 pads | emb->bf16+transpose+norm | init
__global__ __launch_bounds__(256) void k_prep(const float* __restrict__ X,
                                              const float* __restrict__ emb,
                                              unsigned short* __restrict__ Xpad,
                                              unsigned short* __restrict__ Xodd,
                                              unsigned short* __restrict__ Ebf,
                                              float* __restrict__ Etf,
                                              float* __restrict__ enorm,
                                              int* __restrict__ hist,
                                              int* __restrict__ cmax) {
    __shared__ float red[256];
    const int q = blockIdx.x;
    const int tid = threadIdx.x;
    if (q < 32) {
        const int b = q >> 2, seg = q & 3;
        for (int i = seg * 2560 + tid; i < (seg + 1) * 2560; i += 256) {
            unsigned short v = 0, vo = 0;
            if (i >= 512 && i < 512 + LL) v = f2bf(X[b * LL + (i - 512)]);
            const int i1 = i + 1;
            if (i1 >= 512 && i1 < 512 + LL) vo = f2bf(X[b * LL + (i1 - 512)]);
            Xpad[b * XPS + i] = v;
            Xodd[b * XPS + i] = vo;        // Xodd[i] = Xpad[i+1]
        }
    } else if (q < 288) {
        const int e = q - 32;
        const float* er = emb + e * KK;
        float nrm = 0.f;
        for (int k = tid; k < 1024; k += 256) {
            float v = (k < KK) ? er[k] : 0.f;
            Ebf[e * 1024 + k] = (k < KK) ? f2bf(v) : (unsigned short)0;
            Etf[(k >> 2) * 1024 + e * 4 + (k & 3)] = v;   // float4 [t4][e]
            nrm = fmaf(v, v, nrm);
        }
        red[tid] = nrm;
        __syncthreads();
        for (int off = 128; off; off >>= 1) {
            if (tid < off) red[tid] += red[tid + off];
            __syncthreads();
        }
        if (tid == 0) enorm[e] = red[0];
    } else {
        const int i = (q - 288) * 256 + tid;
        cmax[i] = INT_MIN;
        if (q == 288) hist[tid] = 0;
    }
}

// ---------------- K1: autocov (2 lags/thread, float2 register window) --------
__global__ __launch_bounds__(256) void k_autocov(const float* __restrict__ X,
                                                 float* __restrict__ Z) {
    __shared__ __align__(16) float xw[2046];
    __shared__ float red[256];
    const int fi = blockIdx.x >> 1, half = blockIdx.x & 1;
    const int b = fi >> 4, h = fi & 15;
    const int tid = threadIdx.x;
    const float* xp = X + b * LL + c_pos[h];

    float lmax = 0.f;
    for (int j = tid; j < KK; j += 256) {
        float v = xp[j];
        xw[j] = v;
        lmax = fmaxf(lmax, fabsf(v));
    }
    red[tid] = lmax;
    __syncthreads();
    for (int off = 128; off; off >>= 1) {
        if (tid < off) red[tid] = fmaxf(red[tid], red[tid + off]);
        __syncthreads();
    }
    float fmx = red[0];
    if (fmx == 0.f) fmx = EPSF;
    __syncthreads();
    for (int j = tid; j < KK; j += 256) {
        float v = xw[j];
        float win = 0.5f * (1.0f - cosf(6.28318530717958647692f * (float)j / 1023.0f));
        float w = v * win / fmx;
        xw[j] = w;
        xw[j + KK] = w;        // duplicate: c[m] = sum_j xw[j]*xw[j+m], no modulo
    }
    __syncthreads();

    const int m2 = half * 512 + 2 * tid;
    const int mh = m2 >> 1;
    const float2* X2 = (const float2*)xw;
    float a0 = 0.f, a1 = 0.f;
    float2 F = X2[mh];
#pragma unroll 4
    for (int jh = 0; jh < 511; ++jh) {
        float2 xj = X2[jh];                 // uniform broadcast
        float2 G = X2[mh + jh + 1];
        a0 = fmaf(xj.x, F.x, a0);
        a0 = fmaf(xj.y, F.y, a0);
        a1 = fmaf(xj.x, F.y, a1);
        a1 = fmaf(xj.y, G.x, a1);
        F = G;
    }
    float xt = xw[1022];
    a0 = fmaf(xt, F.x, a0);
    a1 = fmaf(xt, F.y, a1);
    float* zrow = Z + fi * KK;
    int i0 = m2 + 512; if (i0 >= KK) i0 -= KK;   // Z[i] = c[(i+511)%1023]
    zrow[i0] = a0;
    if (m2 + 1 < KK) {
        int i1 = m2 + 513; if (i1 >= KK) i1 -= KK;
        zrow[i1] = a1;
    }
}

// ---------------- K2: VQ argmin + vq-loss partial + histogram ----------------
__global__ __launch_bounds__(256) void k_vq(const float* __restrict__ Z,
                                            const float4* __restrict__ Et4,
                                            const float* __restrict__ enorm,
                                            const float* __restrict__ emb,
                                            int* __restrict__ codes,
                                            int* __restrict__ hist,
                                            float* __restrict__ vq_part) {
    __shared__ float zl[KK];
    __shared__ __align__(16) float zm2[1024];
    __shared__ float rv[256];
    __shared__ int   ri[256];
    const int fi = blockIdx.x, tid = threadIdx.x;
    const float* zrow = Z + fi * KK;
    for (int t = tid; t < 1024; t += 256) {
        float z = (t < KK) ? zrow[t] : 0.f;
        if (t < KK) zl[t] = z;
        zm2[t] = -2.f * z;
    }
    __syncthreads();

    float d = enorm[tid];
    const float4* zp = (const float4*)zm2;
    const float4* ep = Et4 + tid;
#pragma unroll 8
    for (int t4 = 0; t4 < 256; ++t4) {
        float4 ev = ep[t4 * 256];     // coalesced: lane stride 16B
        float4 zv = zp[t4];           // LDS broadcast
        d = fmaf(zv.x, ev.x, d);
        d = fmaf(zv.y, ev.y, d);
        d = fmaf(zv.z, ev.z, d);
        d = fmaf(zv.w, ev.w, d);
    }
    rv[tid] = d; ri[tid] = tid;
    __syncthreads();
    for (int off = 128; off; off >>= 1) {
        if (tid < off) {
            float v2 = rv[tid + off]; int i2 = ri[tid + off];
            if (v2 < rv[tid] || (v2 == rv[tid] && i2 < ri[tid])) { rv[tid] = v2; ri[tid] = i2; }
        }
        __syncthreads();
    }
    const int code = ri[0];
    if (tid == 0) { codes[fi] = code; atomicAdd(&hist[code], 1); }

    const float* qr = emb + code * KK;
    float s = 0.f;
    for (int t = tid; t < KK; t += 256) { float dd = qr[t] - zl[t]; s += dd * dd; }
    __syncthreads();
    rv[tid] = s;
    __syncthreads();
    for (int off = 128; off; off >>= 1) {
        if (tid < off) rv[tid] += rv[tid + off];
        __syncthreads();
    }
    if (tid == 0) vq_part[fi] = rv[0];
}

// ---------------- K3: merged MFMA implicit-GEMM, FULL N coverage ----------------
__global__ __launch_bounds__(512, 2) void k_gemm(const unsigned short* __restrict__ Xpad,
                                                 const unsigned short* __restrict__ Xodd,
                                                 const unsigned short* __restrict__ Ebf,
                                                 const int* __restrict__ codes,
                                                 const float* __restrict__ X,
                                                 float* __restrict__ psum_part,
                                                 float* __restrict__ recon_part,
                                                 int* __restrict__ cmax) {
    __shared__ __align__(16) unsigned short lds_b[16 * 1536];  // 49152 B: 16 windows
    __shared__ __align__(16) unsigned short lds_a[2 * 4096];   // 16384 B: A dbuf [128][32]
    __shared__ float red_s[2][64][4];
    const int tid  = threadIdx.x;
    const int lane = tid & 63;
    const int c = lane & 15, g = lane >> 4;
    const int w = tid >> 6, we = w & 1, wg = w >> 1;

    const int bi = blockIdx.x;
    const bool isproj = bi < 512;
    int b, l0, e0;
    if (isproj) { b = bi >> 6; int r = bi & 63; e0 = (r >> 5) * 128; l0 = (r & 31) * 256; }
    else        { int q = bi - 512; b = q >> 5; e0 = 0; l0 = (q & 31) * 256; }
    const int xw0 = (isproj ? 512 : 0) + l0;

    {
        const unsigned short* base_e = Xpad + b * XPS;
        const unsigned short* base_o = Xodd + b * XPS;
#pragma unroll
        for (int kk = 0; kk < 2; ++kk) {
            const int wdw = 2 * w + kk;
            const unsigned short* src = (wdw & 1) ? (base_o + xw0 + wdw - 1)
                                                  : (base_e + xw0 + wdw);
#pragma unroll
            for (int p = 0; p < 3; ++p)
                gl2lds16(src + p * 512 + lane * 8, lds_b + wdw * 1536 + p * 512 + lane * 8);
        }
    }
    const int r_lds = tid >> 2, q4 = tid & 3;
    const int grow = isproj ? (e0 + r_lds) : codes[r_lds];
    const unsigned short* e_src = Ebf + grow * 1024 + q4 * 8;
    gl2lds16(e_src, lds_a + tid * 8);
    __syncthreads();

    f32x4 acc[4][4];
#pragma unroll
    for (int i = 0; i < 4; ++i)
#pragma unroll
        for (int j = 0; j < 4; ++j) acc[i][j] = (f32x4){0.f, 0.f, 0.f, 0.f};

    const char* lax = (const char*)lds_a;
    const char* lbx = (const char*)lds_b;
    const int boff0 = (wg * 4) * 3072 + 32 * c + 16 * g;
    const int aoff0 = we * 4096 + c * 64 + g * 16;

    for (int s = 0; s < 32; ++s) {
        const int cur = s & 1;
        if (s + 1 < 32)
            gl2lds16(e_src + (s + 1) * 32, lds_a + ((s + 1) & 1) * 4096 + tid * 8);
        const char* ab = lax + cur * 8192 + aoff0;
        bf16x8 af[4];
#pragma unroll
        for (int et = 0; et < 4; ++et) af[et] = *(const bf16x8*)(ab + et * 1024);
#pragma unroll
        for (int ntl = 0; ntl < 4; ++ntl) {
            bf16x8 bfrag = *(const bf16x8*)(lbx + boff0 + ntl * 3072 + 64 * s);
#pragma unroll
            for (int et = 0; et < 4; ++et)
                acc[et][ntl] = __builtin_amdgcn_mfma_f32_16x16x32_bf16(af[et], bfrag, acc[et][ntl], 0, 0, 0);
        }
        __syncthreads();
    }

    const int lseg  = l0 >> 8;
    const int lbase = l0 + wg * 4;         // l = lbase + ntl + 16*c
    if (isproj) {
        const int ch0 = lbase / 896;
#pragma unroll
        for (int et = 0; et < 4; ++et) {
#pragma unroll
            for (int r = 0; r < 4; ++r) {
                float ssum = 0.f, m0 = NEG_INF, m1 = NEG_INF;
#pragma unroll
                for (int ntl = 0; ntl < 4; ++ntl) {
                    float v = acc[et][ntl][r];
                    int l = lbase + ntl + 16 * c;
                    bool ok = l < LO;
                    ssum += ok ? v : 0.f;
                    int ch = l / 896;
                    if (ok && ch == ch0) m0 = fmaxf(m0, v);
                    if (ok && ch != ch0) m1 = fmaxf(m1, v);
                }
                ssum += __shfl_xor(ssum, 1); ssum += __shfl_xor(ssum, 2);
                ssum += __shfl_xor(ssum, 4); ssum += __shfl_xor(ssum, 8);
                m0 = fmaxf(m0, __shfl_xor(m0, 1)); m0 = fmaxf(m0, __shfl_xor(m0, 2));
                m0 = fmaxf(m0, __shfl_xor(m0, 4)); m0 = fmaxf(m0, __shfl_xor(m0, 8));
                m1 = fmaxf(m1, __shfl_xor(m1, 1)); m1 = fmaxf(m1, __shfl_xor(m1, 2));
                m1 = fmaxf(m1, __shfl_xor(m1, 4)); m1 = fmaxf(m1, __shfl_xor(m1, 8));
                if (c == 0) {
                    int eidx = et * 16 + g * 4 + r;
                    red_s[we][eidx][wg] = ssum;
                    int e = e0 + we * 64 + eidx;
                    int cb = (b * 256 + e) * 8;
                    if (m0 > NEG_INF && ch0 < 8)     atomicMax(&cmax[cb + ch0], fenc(m0));
                    if (m1 > NEG_INF && ch0 + 1 < 8) atomicMax(&cmax[cb + ch0 + 1], fenc(m1));
                }
            }
        }
    } else {
        float xv[4];
#pragma unroll
        for (int ntl = 0; ntl < 4; ++ntl) {
            int lr = lbase + ntl + 16 * c - 1;
            xv[ntl] = (lr >= 0 && lr < LL) ? X[b * LL + lr] : 0.f;
        }
#pragma unroll
        for (int et = 0; et < 4; ++et) {
#pragma unroll
            for (int r = 0; r < 4; ++r) {
                float ssum = 0.f;
#pragma unroll
                for (int ntl = 0; ntl < 4; ++ntl) {
                    int lr = lbase + ntl + 16 * c - 1;
                    bool ok = (lr >= 0) && (lr < LL);
                    float dd = ok ? (acc[et][ntl][r] - xv[ntl]) : 0.f;
                    ssum += dd * dd;
                }
                ssum += __shfl_xor(ssum, 1); ssum += __shfl_xor(ssum, 2);
                ssum += __shfl_xor(ssum, 4); ssum += __shfl_xor(ssum, 8);
                if (c == 0) red_s[we][et * 16 + g * 4 + r][wg] = ssum;
            }
        }
    }
    __syncthreads();
    if (tid < 128) {
        const int wwe = tid >> 6, eidx = tid & 63;
        float tot = red_s[wwe][eidx][0] + red_s[wwe][eidx][1]
                  + red_s[wwe][eidx][2] + red_s[wwe][eidx][3];
        if (isproj) {
            int e = e0 + wwe * 64 + eidx;
            psum_part[lseg * 2048 + b * 256 + e] = tot;   // [lseg][b*256+e]
        } else {
            int f = wwe * 64 + eidx;
            recon_part[(b * 128 + f) * 32 + lseg] = tot;
        }
    }
}

// ---------------- K5: combine pooling + LayerNorm over E ----------------
__global__ __launch_bounds__(256) void k_ln(const float* __restrict__ psum_part,
                                            const int* __restrict__ cmax,
                                            const float* __restrict__ ln_g,
                                            const float* __restrict__ ln_b,
                                            float* __restrict__ xn) {
    __shared__ float red[256];
    __shared__ float red2[256];
    const int bt = blockIdx.x;      // b*8 + t
    const int t = bt & 7;
    const int b = bt >> 3;
    const int e = threadIdx.x;
    const float* ps = psum_part + b * 256 + e;
    float sm = 0.f;
#pragma unroll
    for (int s = 0; s < 32; ++s) sm += ps[s * 2048];   // coalesced per step
    float m = sm * (1.0f / 7162.0f);
    const int cb = (b * 256 + e) << 3;
    float v = (t < 7) ? fdec(cmax[cb + t]) : fmaxf(fdec(cmax[cb + 7]), m);
    red[e] = v; red2[e] = v * v;
    __syncthreads();
    for (int off = 128; off; off >>= 1) {
        if (e < off) { red[e] += red[e + off]; red2[e] += red2[e + off]; }
        __syncthreads();
    }
    float mu  = red[0] * (1.0f / 256.0f);
    float var = red2[0] * (1.0f / 256.0f) - mu * mu;
    float r = 1.0f / sqrtf(var + 1e-5f);
    xn[bt * 256 + e] = (v - mu) * r * ln_g[e] + ln_b[e];
}

// ---------------- K6a: FFN layer 1 (relu(xn@w1+b1)), K-split x4 ----------------
// grid 512: bt = q&63, jc = q>>6 (8 chunks of 64 j). Wave ks handles K chunk of 64.
__global__ __launch_bounds__(256) void k_ffn1(const float* __restrict__ xn,
                                              const float* __restrict__ w1,
                                              const float* __restrict__ b1,
                                              float* __restrict__ hbuf) {
    __shared__ float xr[256];
    __shared__ float rv[256];
    const int q = blockIdx.x;
    const int bt = q & 63, jc = q >> 6;
    const int tid = threadIdx.x;
    xr[tid] = xn[bt * 256 + tid];
    __syncthreads();
    const int jj = tid & 63, ks = tid >> 6;
    const int j = jc * 64 + jj;
    const float* wp = w1 + (ks * 64) * 512 + j;
    float a = 0.f;
#pragma unroll
    for (int ee = 0; ee < 64; ++ee) a = fmaf(xr[ks * 64 + ee], wp[ee * 512], a);
    rv[tid] = a;
    __syncthreads();
    if (tid < 64) {
        float s = rv[tid] + rv[tid + 64] + rv[tid + 128] + rv[tid + 192];
        hbuf[bt * 512 + jc * 64 + tid] = fmaxf(s + b1[jc * 64 + tid], 0.f);
    }
}

// ---------------- K6b: FFN layer 2 (h@w2+b2), K-split x4 ----------------
// grid 256: bt = q&63, jc = q>>6 (4 chunks of 64 e). Wave ks handles K chunk of 128.
__global__ __launch_bounds__(256) void k_ffn2(const float* __restrict__ hbuf,
                                              const float* __restrict__ w2,
                                              const float* __restrict__ b2,
                                              float* __restrict__ hdd) {
    __shared__ float hr[512];
    __shared__ float rv[256];
    const int q = blockIdx.x;
    const int bt = q & 63, jc = q >> 6;
    const int tid = threadIdx.x;
    hr[tid] = hbuf[bt * 512 + tid];
    hr[tid + 256] = hbuf[bt * 512 + 256 + tid];
    __syncthreads();
    const int jj = tid & 63, ks = tid >> 6;
    const int e = jc * 64 + jj;
    const float* wp = w2 + (ks * 128) * 256 + e;
    float a = 0.f;
#pragma unroll
    for (int j = 0; j < 128; ++j) a = fmaf(hr[ks * 128 + j], wp[j * 256], a);
    rv[tid] = a;
    __syncthreads();
    if (tid < 64) {
        float s = rv[tid] + rv[tid + 64] + rv[tid + 128] + rv[tid + 192];
        hdd[bt * 256 + jc * 64 + tid] = s + b2[jc * 64 + tid];
    }
}

// ---------------- K7: block0 = feat-mean + classifier; block1 = scalar losses --
__global__ __launch_bounds__(256) void k_final(const float* __restrict__ hdd,
                                               const float* __restrict__ cls_w,
                                               const float* __restrict__ cls_b,
                                               const float* __restrict__ recon_part,
                                               const float* __restrict__ vq_part,
                                               const int* __restrict__ hist,
                                               float* __restrict__ out) {
    __shared__ float red[256];
    const int tid = threadIdx.x;
    if (blockIdx.x == 0) {
        __shared__ float feat[8][256];
#pragma unroll
        for (int b2 = 0; b2 < 8; ++b2) {
            float fb = 0.f;
#pragma unroll
            for (int t2 = 0; t2 < 8; ++t2) fb += hdd[(b2 * 8 + t2) * 256 + tid];
            feat[b2][tid] = fb * 0.125f;
        }
        __syncthreads();
        if (tid < 80) {
            const int b = tid / 10, k = tid % 10;
            float a = cls_b[k];
            for (int e = 0; e < 256; ++e) a = fmaf(feat[b][e], cls_w[e * 10 + k], a);
            out[tid] = a;
        }
    } else {
        float s = 0.f;
        for (int i = tid; i < 32768; i += 256) s += recon_part[i];
        red[tid] = s;
        __syncthreads();
        for (int off = 128; off; off >>= 1) { if (tid < off) red[tid] += red[tid + off]; __syncthreads(); }
        if (tid == 0) out[81] = red[0] / 1047552.0f;
        __syncthreads();
        red[tid] = (tid < 128) ? vq_part[tid] : 0.f;
        __syncthreads();
        for (int off = 128; off; off >>= 1) { if (tid < off) red[tid] += red[tid + off]; __syncthreads(); }
        if (tid == 0) out[80] = 1.25f * red[0] / 130944.0f;
        __syncthreads();
        float avg = (float)hist[tid] * (1.0f / 128.0f);
        red[tid] = avg * logf(avg + EPSF);
        __syncthreads();
        for (int off = 128; off; off >>= 1) { if (tid < off) red[tid] += red[tid + off]; __syncthreads(); }
        if (tid == 0) out[82] = expf(-red[0]);
    }
}

extern "C" void kernel_launch(void* const* d_in, const int* in_sizes, int n_in,
                              void* d_out, int out_size, void* d_ws, size_t ws_size,
                              hipStream_t stream) {
    const float* X     = (const float*)d_in[0];
    const float* emb   = (const float*)d_in[1];
    const float* w1    = (const float*)d_in[2];
    const float* b1    = (const float*)d_in[3];
    const float* w2    = (const float*)d_in[4];
    const float* b2    = (const float*)d_in[5];
    const float* ln_g  = (const float*)d_in[6];
    const float* ln_b  = (const float*)d_in[7];
    const float* cls_w = (const float*)d_in[8];
    const float* cls_b = (const float*)d_in[9];
    float* out = (float*)d_out;

    float* Z            = (float*)d_ws;            // 130944
    float* vq_part      = Z + 130944;              // 128
    float* xnbuf        = vq_part + 128;           // 16384
    float* hdd          = xnbuf + 16384;           // 16384
    float* psum_part    = hdd + 16384;             // 65536  [lseg][b*256+e]
    float* recon_part   = psum_part + 65536;       // 32768
    int*   cmaxb        = (int*)(recon_part + 32768);  // 16384
    int*   codes        = cmaxb + 16384;           // 128
    int*   hist         = codes + 128;             // 256
    unsigned short* Xpad = (unsigned short*)(hist + 256);   // 8*10240 shorts
    unsigned short* Xodd = Xpad + 8 * XPS;                  // 8*10240 shorts
    unsigned short* Ebf  = Xodd + 8 * XPS;                  // 256*1024 shorts
    float* Etf           = (float*)(Ebf + 256 * 1024);      // 256*1024 floats
    float* enorm         = Etf + 256 * 1024;                // 256
    float* hbuf          = enorm + 256;                     // 64*512

    k_prep   <<<dim3(352), dim3(256), 0, stream>>>(X, emb, Xpad, Xodd, Ebf, Etf, enorm, hist, cmaxb);
    k_autocov<<<dim3(256), dim3(256), 0, stream>>>(X, Z);
    k_vq     <<<dim3(128), dim3(256), 0, stream>>>(Z, (const float4*)Etf, enorm, emb, codes, hist, vq_part);
    k_gemm   <<<dim3(768), dim3(512), 0, stream>>>(Xpad, Xodd, Ebf, codes, X, psum_part, recon_part, cmaxb);
    k_ln     <<<dim3(64),  dim3(256), 0, stream>>>(psum_part, cmaxb, ln_g, ln_b, xnbuf);
    k_ffn1   <<<dim3(512), dim3(256), 0, stream>>>(xnbuf, w1, b1, hbuf);
    k_ffn2   <<<dim3(256), dim3(256), 0, stream>>>(hbuf, w2, b2, hdd);
    k_final  <<<dim3(2),   dim3(256), 0, stream>>>(hdd, cls_w, cls_b, recon_part, vq_part, hist, out);
}